// Round 11
// baseline (3148.513 us; speedup 1.0000x reference)
//
#include <hip/hip_runtime.h>

#define NB 4
#define NT 32
#define ND 768
#define NK 1024
#define NN 256
#define NINIT 4
#define NFRAMES 28
#define NM 1280

typedef _Float16 f16;
typedef f16 f16x8 __attribute__((ext_vector_type(8)));
typedef f16 f16x4 __attribute__((ext_vector_type(4)));
typedef float f32x4 __attribute__((ext_vector_type(4)));

#define GLOAD_LDS(g, s) __builtin_amdgcn_global_load_lds( \
    (const __attribute__((address_space(1))) void*)(g),   \
    (__attribute__((address_space(3))) void*)(s), 16, 0, 0)

// row-dependent XOR swizzle, closed within a 64-byte row (bits 4-5 only).
__device__ __forceinline__ int swz(int r) { return ((r >> 1) & 3) << 4; }

// ---------------- init: mem copy, counts=1, f16 split, cnorm partials, reset --
__global__ __launch_bounds__(256) void k_init(
    const float* __restrict__ V, float* __restrict__ mem, float* __restrict__ cnt,
    f16* __restrict__ mH, f16* __restrict__ mL,
    float* __restrict__ cnP, unsigned long long* __restrict__ packed0)
{
    int row = blockIdx.x * 4 + (threadIdx.x >> 6);   // 0..4095
    int lane = threadIdx.x & 63;
    int b = row >> 10, k = row & 1023;
    const float4* src = (const float4*)(V + ((size_t)b * NT * NN + k) * ND);
    float4* mrow = (float4*)(mem + (size_t)row * ND);
    f16x4* hrow = (f16x4*)(mH + (size_t)row * ND);
    f16x4* lrow = (f16x4*)(mL + (size_t)row * ND);
    float s2 = 0.f;
#pragma unroll
    for (int jj = 0; jj < 3; ++jj) {
        float4 x = src[lane + 64 * jj];
        mrow[lane + 64 * jj] = x;
        f16x4 h, lo;
        h[0] = (f16)x.x; lo[0] = (f16)(x.x - (float)h[0]);
        h[1] = (f16)x.y; lo[1] = (f16)(x.y - (float)h[1]);
        h[2] = (f16)x.z; lo[2] = (f16)(x.z - (float)h[2]);
        h[3] = (f16)x.w; lo[3] = (f16)(x.w - (float)h[3]);
        hrow[lane + 64 * jj] = h;
        lrow[lane + 64 * jj] = lo;
        s2 += x.x * x.x + x.y * x.y + x.z * x.z + x.w * x.w;
    }
#pragma unroll
    for (int off = 32; off; off >>= 1) s2 += __shfl_xor(s2, off);
    if (lane == 0) {
        cnP[row * 3] = s2; cnP[row * 3 + 1] = 0.f; cnP[row * 3 + 2] = 0.f;
        cnt[row] = 1.0f; packed0[(size_t)b * NM + k] = ~0ull;
    }
    if (lane == 1 && k < NN) packed0[(size_t)b * NM + NK + k] = ~0ull;
}

// ---------------- token split: frames t0..t0+nF-1 -> slots 0..nF-1 ----------
__global__ __launch_bounds__(256) void k_prep(
    const float* __restrict__ V, int t0, int nF,
    f16* __restrict__ tokH, f16* __restrict__ tokL, size_t tokBS)
{
    int g = blockIdx.x * 4 + (threadIdx.x >> 6);
    int lane = threadIdx.x & 63;
    int perB = nF * NN;
    if (g >= NB * perB) return;
    int b = g / perB;
    int rem = g - b * perB;
    int fi = rem / NN, n = rem - fi * NN;
    const float4* src = (const float4*)(V + (((size_t)b * NT + t0 + fi) * NN + n) * ND);
    f16x4* hrow = (f16x4*)(tokH + (size_t)b * tokBS + (size_t)(fi * NN + n) * ND);
    f16x4* lrow = (f16x4*)(tokL + (size_t)b * tokBS + (size_t)(fi * NN + n) * ND);
#pragma unroll
    for (int jj = 0; jj < 3; ++jj) {
        float4 x = src[lane + 64 * jj];
        f16x4 h, lo;
        h[0] = (f16)x.x; lo[0] = (f16)(x.x - (float)h[0]);
        h[1] = (f16)x.y; lo[1] = (f16)(x.y - (float)h[1]);
        h[2] = (f16)x.z; lo[2] = (f16)(x.z - (float)h[2]);
        h[3] = (f16)x.w; lo[3] = (f16)(x.w - (float)h[3]);
        hrow[lane + 64 * jj] = h;
        lrow[lane + 64 * jj] = lo;
    }
}

// ---------------- iter1 MFMA score: split-D 8-wave blocks (MT=64) -----------
// A = frame tokens (256 rows), B = memory split (1024 rows).
__global__ __launch_bounds__(512) void k_score1(
    const f16* __restrict__ TH, const f16* __restrict__ TL, size_t tokBS,
    const f16* __restrict__ BH, const f16* __restrict__ BL,
    const float* __restrict__ cnP,
    unsigned long long* __restrict__ packed)
{
    constexpr int MT = 64;
    constexpr int FM = MT / 32;            // 2
    constexpr int QROWS = MT / 2;          // 32
    constexpr int ASL = MT / 16;           // 4
    constexpr int SLOTS = 2 * ASL + 8;     // 16
    constexpr int SPW = SLOTS / 4;         // 4
    constexpr int RSZ = SLOTS * 1024;

    __shared__ float4 ldsbuf[SLOTS * 128];
    char* lds = (char*)ldsbuf;

    int bid = blockIdx.x;                  // 256 blocks: 4b x 4mt x 16kt
    int cpx = (int)gridDim.x >> 3;
    int sz = (bid & 7) * cpx + (bid >> 3);
    int b = sz / 64;
    int rem = sz - b * 64;
    int mt = rem >> 4, kt = rem & 15;
    int tid = threadIdx.x;
    int w = tid >> 6, l = tid & 63;
    int h = w >> 2, q = w & 3;
    int wm = q >> 1, wk = q & 1;
    const int REG = h * RSZ;

    const char* sp[SPW];
#pragma unroll
    for (int i = 0; i < SPW; ++i) {
        int slot = q * SPW + i;
        const f16* base; int r;
        if (slot < ASL)            { r = slot * 16 + (l >> 2);             base = TH + (size_t)b * tokBS + (size_t)(mt * MT + r) * ND; }
        else if (slot < 2 * ASL)   { r = (slot - ASL) * 16 + (l >> 2);     base = TL + (size_t)b * tokBS + (size_t)(mt * MT + r) * ND; }
        else if (slot < 2*ASL + 4) { r = (slot - 2*ASL) * 16 + (l >> 2);   base = BH + ((size_t)b * NK + kt * 64 + r) * ND; }
        else                       { r = (slot - 2*ASL - 4) * 16 + (l >> 2); base = BL + ((size_t)b * NK + kt * 64 + r) * ND; }
        int colB = ((l & 3) * 16) ^ swz(r);
        sp[i] = (const char*)base + h * 768 + colB;
    }

    int aoffH[FM], aoffL[FM], boffH[2], boffL[2];
#pragma unroll
    for (int mi = 0; mi < FM; ++mi) {
        int r = wm * QROWS + mi * 16 + (l & 15);
        int off = r * 64 + (((l >> 4) * 16) ^ swz(r));
        aoffH[mi] = REG + off;
        aoffL[mi] = REG + ASL * 1024 + off;
    }
#pragma unroll
    for (int nj = 0; nj < 2; ++nj) {
        int rB = wk * 32 + nj * 16 + (l & 15);
        int off = rB * 64 + (((l >> 4) * 16) ^ swz(rB));
        boffH[nj] = REG + 2 * ASL * 1024 + off;
        boffL[nj] = REG + 2 * ASL * 1024 + 4096 + off;
    }

    f32x4 acc[FM][2] = {};

    for (int c = 0; c < 12; ++c) {
#pragma unroll
        for (int i = 0; i < SPW; ++i) {
            GLOAD_LDS(sp[i], lds + REG + (q * SPW + i) * 1024);
            sp[i] += 64;
        }
        __syncthreads();
        f16x8 ah[FM], al[FM], bh[2], bl[2];
#pragma unroll
        for (int mi = 0; mi < FM; ++mi) {
            ah[mi] = *(const f16x8*)(lds + aoffH[mi]);
            al[mi] = *(const f16x8*)(lds + aoffL[mi]);
        }
#pragma unroll
        for (int nj = 0; nj < 2; ++nj) {
            bh[nj] = *(const f16x8*)(lds + boffH[nj]);
            bl[nj] = *(const f16x8*)(lds + boffL[nj]);
        }
#pragma unroll
        for (int mi = 0; mi < FM; ++mi)
#pragma unroll
            for (int nj = 0; nj < 2; ++nj) {
                acc[mi][nj] = __builtin_amdgcn_mfma_f32_16x16x32_f16(ah[mi], bh[nj], acc[mi][nj], 0, 0, 0);
                acc[mi][nj] = __builtin_amdgcn_mfma_f32_16x16x32_f16(ah[mi], bl[nj], acc[mi][nj], 0, 0, 0);
                acc[mi][nj] = __builtin_amdgcn_mfma_f32_16x16x32_f16(al[mi], bh[nj], acc[mi][nj], 0, 0, 0);
            }
        __syncthreads();
    }

    int coff = q * (QROWS * 128) + l * 16;
    if (h == 1) {
#pragma unroll
        for (int mi = 0; mi < FM; ++mi)
#pragma unroll
            for (int nj = 0; nj < 2; ++nj)
                *(f32x4*)(lds + coff + (mi * 2 + nj) * 1024) = acc[mi][nj];
    }
    __syncthreads();
    if (h != 0) return;
#pragma unroll
    for (int mi = 0; mi < FM; ++mi)
#pragma unroll
        for (int nj = 0; nj < 2; ++nj)
            acc[mi][nj] += *(const f32x4*)(lds + coff + (mi * 2 + nj) * 1024);

    int colb = kt * 64 + wk * 32 + (l & 15);
    float cn[2];
#pragma unroll
    for (int nj = 0; nj < 2; ++nj) {
        int kc = b * NK + colb + nj * 16;
        cn[nj] = cnP[kc * 3] + cnP[kc * 3 + 1] + cnP[kc * 3 + 2];
    }
    size_t prow = (size_t)b * NM + NK + mt * MT + wm * QROWS + (l >> 4) * 4;
#pragma unroll
    for (int mi = 0; mi < FM; ++mi) {
#pragma unroll
        for (int rg = 0; rg < 4; ++rg) {
            float bv = 1e30f; int bi = 0;
#pragma unroll
            for (int nj = 0; nj < 2; ++nj) {
                float s = cn[nj] - 2.0f * acc[mi][nj][rg];
                int ki = colb + nj * 16;
                if (s < bv) { bv = s; bi = ki; }
            }
#pragma unroll
            for (int off = 1; off < 16; off <<= 1) {
                float ov = __shfl_xor(bv, off);
                int   oi = __shfl_xor(bi, off);
                if (ov < bv || (ov == bv && oi < bi)) { bv = ov; bi = oi; }
            }
            if ((l & 15) == 0) {
                unsigned u = __float_as_uint(bv);
                unsigned key = (u >> 31) ? ~u : (u | 0x80000000u);
                atomicMin(&packed[prow + mi * 16 + rg],
                          ((unsigned long long)key << 32) | (unsigned)bi);
            }
        }
    }
}

// -------- iter2 score: 128x64 tile, 640 blocks, 4-wave dbuf + vmcnt(6) ------
// A rows 0..1023 = memory split, 1024..1279 = frame tokens (block-uniform mt).
__global__ __launch_bounds__(256) void k_score2(
    const f16* __restrict__ MH, const f16* __restrict__ ML,
    const f16* __restrict__ TH, const f16* __restrict__ TL, size_t tokBS,
    const f16* __restrict__ CH, const f16* __restrict__ CL,
    const float* __restrict__ cnP,
    unsigned long long* __restrict__ packed)
{
    __shared__ float4 ldsbuf[3072];   // 48 KB: 2 buffers x 24 KB
    char* lds = (char*)ldsbuf;
    int bid = blockIdx.x;
    int cpx = (int)gridDim.x >> 3;
    int sz = (bid & 7) * cpx + (bid >> 3);     // XCD-aware (640 % 8 == 0)
    int b = sz / 160;
    int rem = sz - b * 160;
    int mt = rem >> 4, kt = rem & 15;
    int tid = threadIdx.x;
    int w = tid >> 6, l = tid & 63;
    int wm = w >> 1, wk = w & 1;

    const char* sp[6];
#pragma unroll
    for (int i = 0; i < 6; ++i) {
        int j = w * 6 + i;
        const f16* base; int r;
        if (j < 8) {
            r = 16 * j + (l >> 2);
            int R = mt * 128 + r;
            base = (mt < 8) ? MH + ((size_t)b * NK + R) * ND
                            : TH + (size_t)b * tokBS + (size_t)(R - NK) * ND;
        } else if (j < 16) {
            r = 16 * (j - 8) + (l >> 2);
            int R = mt * 128 + r;
            base = (mt < 8) ? ML + ((size_t)b * NK + R) * ND
                            : TL + (size_t)b * tokBS + (size_t)(R - NK) * ND;
        } else if (j < 20) {
            r = 16 * (j - 16) + (l >> 2);
            base = CH + ((size_t)b * NK + kt * 64 + r) * ND;
        } else {
            r = 16 * (j - 20) + (l >> 2);
            base = CL + ((size_t)b * NK + kt * 64 + r) * ND;
        }
        int colB = ((l & 3) * 16) ^ swz(r);
        sp[i] = (const char*)base + colB;
    }

    int aoff[4], boff[2];
#pragma unroll
    for (int mi = 0; mi < 4; ++mi) {
        int r = wm * 64 + mi * 16 + (l & 15);
        aoff[mi] = r * 64 + (((l >> 4) * 16) ^ swz(r));
    }
#pragma unroll
    for (int nj = 0; nj < 2; ++nj) {
        int r = wk * 32 + nj * 16 + (l & 15);
        boff[nj] = 16384 + r * 64 + (((l >> 4) * 16) ^ swz(r));
    }

    f32x4 acc[4][2] = {};

#define STAGEB(bufbase)                                        \
    _Pragma("unroll")                                          \
    for (int i = 0; i < 6; ++i) {                              \
        GLOAD_LDS(sp[i], lds + (bufbase) + (w * 6 + i) * 1024);\
        sp[i] += 64;                                           \
    }

    STAGEB(0);
    for (int c = 0; c < 24; ++c) {
        int cur = (c & 1) ? 24576 : 0;
        if (c < 23) {
            STAGEB(cur ^ 24576);
            asm volatile("s_waitcnt vmcnt(6)" ::: "memory");
        } else {
            asm volatile("s_waitcnt vmcnt(0)" ::: "memory");
        }
        __builtin_amdgcn_s_barrier();
        __builtin_amdgcn_sched_barrier(0);
        f16x8 ah[4], al[4], bh[2], bl[2];
#pragma unroll
        for (int mi = 0; mi < 4; ++mi) {
            ah[mi] = *(const f16x8*)(lds + cur + aoff[mi]);
            al[mi] = *(const f16x8*)(lds + cur + 8192 + aoff[mi]);
        }
#pragma unroll
        for (int nj = 0; nj < 2; ++nj) {
            bh[nj] = *(const f16x8*)(lds + cur + boff[nj]);
            bl[nj] = *(const f16x8*)(lds + cur + 4096 + boff[nj]);
        }
#pragma unroll
        for (int mi = 0; mi < 4; ++mi)
#pragma unroll
            for (int nj = 0; nj < 2; ++nj) {
                acc[mi][nj] = __builtin_amdgcn_mfma_f32_16x16x32_f16(ah[mi], bh[nj], acc[mi][nj], 0, 0, 0);
                acc[mi][nj] = __builtin_amdgcn_mfma_f32_16x16x32_f16(ah[mi], bl[nj], acc[mi][nj], 0, 0, 0);
                acc[mi][nj] = __builtin_amdgcn_mfma_f32_16x16x32_f16(al[mi], bh[nj], acc[mi][nj], 0, 0, 0);
            }
        __builtin_amdgcn_sched_barrier(0);
        __builtin_amdgcn_s_barrier();
    }

    int colb = kt * 64 + wk * 32 + (l & 15);
    float cn[2];
#pragma unroll
    for (int nj = 0; nj < 2; ++nj) {
        int kc = b * NK + colb + nj * 16;
        cn[nj] = cnP[kc * 3] + cnP[kc * 3 + 1] + cnP[kc * 3 + 2];
    }
    size_t prow = (size_t)b * NM + mt * 128 + wm * 64 + (l >> 4) * 4;
#pragma unroll
    for (int mi = 0; mi < 4; ++mi) {
#pragma unroll
        for (int rg = 0; rg < 4; ++rg) {
            float bv = 1e30f; int bi = 0;
#pragma unroll
            for (int nj = 0; nj < 2; ++nj) {
                float s = cn[nj] - 2.0f * acc[mi][nj][rg];
                int ki = colb + nj * 16;
                if (s < bv) { bv = s; bi = ki; }
            }
#pragma unroll
            for (int off = 1; off < 16; off <<= 1) {
                float ov = __shfl_xor(bv, off);
                int   oi = __shfl_xor(bi, off);
                if (ov < bv || (ov == bv && oi < bi)) { bv = ov; bi = oi; }
            }
            if ((l & 15) == 0) {
                unsigned u = __float_as_uint(bv);
                unsigned key = (u >> 31) ? ~u : (u | 0x80000000u);
                atomicMin(&packed[prow + mi * 16 + rg],
                          ((unsigned long long)key << 32) | (unsigned)bi);
            }
        }
    }
}

// ---------------- build CSR lists (+trimmed iter1 mode) ----------------------
__global__ __launch_bounds__(1024) void k_lists(
    const unsigned long long* __restrict__ packed, int selfSeed,
    unsigned long long* __restrict__ packedOther,
    int2* __restrict__ cb, int* __restrict__ lstIdx, int* __restrict__ ctrOf,
    int* __restrict__ totalPos)
{
    __shared__ int cntL[NK];
    __shared__ int wsum[16];
    __shared__ int cursor[NK];
    __shared__ int aSh[NM];
    __shared__ int totSh;
    int b = blockIdx.x, tid = threadIdx.x;
    cntL[tid] = 0;
    __syncthreads();
    if (selfSeed) {
        if (tid < NN) {
            int a = (int)(unsigned)(packed[(size_t)b * NM + NK + tid] & 0xffffffffull);
            aSh[tid] = a;
            atomicAdd(&cntL[a], 1);
        }
    } else {
        for (int m = tid; m < NM; m += 1024) {
            int a = (int)(unsigned)(packed[(size_t)b * NM + m] & 0xffffffffull);
            aSh[m] = a;
            atomicAdd(&cntL[a], 1);
        }
    }
    for (int m = tid; m < NM; m += 1024)
        packedOther[(size_t)b * NM + m] = ~0ull;
    __syncthreads();
    int v0 = cntL[tid];
    int v = selfSeed ? (v0 ? v0 + 1 : 0) : v0;
    int lane = tid & 63, wv = tid >> 6;
    int x = v;
#pragma unroll
    for (int off = 1; off < 64; off <<= 1) {
        int y = __shfl_up(x, off);
        if (lane >= off) x += y;
    }
    if (lane == 63) wsum[wv] = x;
    __syncthreads();
    if (tid < 16) {
        int s = wsum[tid];
        int e = s;
#pragma unroll
        for (int off = 1; off < 16; off <<= 1) {
            int y = __shfl_up(e, off, 16);
            if (tid >= off) e += y;
        }
        wsum[tid] = e - s;
    }
    __syncthreads();
    int base = x + wsum[wv] - v;
    cursor[tid] = base + ((selfSeed && v0) ? 1 : 0);
    cb[b * NK + tid] = make_int2(v, base);
    if (selfSeed && v0) {
        lstIdx[(size_t)b * NM + base] = tid;
        ctrOf[(size_t)b * NM + base] = tid;
    }
    if (tid == 1023) totSh = base + v;
    __syncthreads();
    if (selfSeed) {
        if (tid < NN) {
            int a = aSh[tid];
            int pos = atomicAdd(&cursor[a], 1);
            lstIdx[(size_t)b * NM + pos] = NK + tid;
            ctrOf[(size_t)b * NM + pos] = a;
        }
        if (tid == 0) {
            int total = totSh;
            int padEnd = (total + 7) & ~7;
            for (int p2 = total; p2 < padEnd; ++p2) {
                lstIdx[(size_t)b * NM + p2] = 0;
                ctrOf[(size_t)b * NM + p2] = -1;
            }
            totalPos[b] = total;
        }
    } else {
        for (int m = tid; m < NM; m += 1024) {
            int a = aSh[m];
            int pos = atomicAdd(&cursor[a], 1);
            lstIdx[(size_t)b * NM + pos] = m;
            ctrOf[(size_t)b * NM + pos] = a;
        }
        if (tid == 0) totalPos[b] = NM;
    }
}

// ---------------- stage A: per-8-position segment partial sums --------------
__global__ __launch_bounds__(256) void k_part(
    const float* __restrict__ memFS, const float* __restrict__ V, int t,
    const float* __restrict__ cntFS,
    const int* __restrict__ lstIdx, const int* __restrict__ ctrOf,
    const int* __restrict__ totalPos,
    float* __restrict__ part, float* __restrict__ partW)
{
    int g = blockIdx.x * 4 + (threadIdx.x >> 6);   // 0..1919
    int l = threadIdx.x & 63;
    int b = g / 480;
    int rem = g - b * 480;
    int seg = rem / 3, c = rem - seg * 3;
    int pos0 = seg * 8;
    if (pos0 >= totalPos[b]) return;
    const int* li = lstIdx + (size_t)b * NM;
    const int* co = ctrOf + (size_t)b * NM;
    int ctr[8]; float wg[8]; float4 xv[8];
#pragma unroll
    for (int i = 0; i < 8; ++i) {
        int p = pos0 + i;
        int cc = co[p];
        int mm = li[p];
        bool pad = cc < 0;
        ctr[i] = pad ? -2 : cc;
        wg[i] = pad ? 0.f : ((mm < NK) ? cntFS[b * NK + mm] : 1.0f);
        int mload = pad ? 0 : mm;
        const float4* dr = (mload < NK)
            ? (const float4*)(memFS + ((size_t)b * NK + mload) * ND)
            : (const float4*)(V + (((size_t)b * NT + t) * NN + (mload - NK)) * (size_t)ND);
        xv[i] = dr[c * 64 + l];
    }
    float4 acc; float sw; int cur = ctr[0];
    acc.x = wg[0] * xv[0].x; acc.y = wg[0] * xv[0].y;
    acc.z = wg[0] * xv[0].z; acc.w = wg[0] * xv[0].w;
    sw = wg[0];
#pragma unroll
    for (int i = 1; i < 8; ++i) {
        if (ctr[i] != cur) {
            int e = pos0 + i - 1;
            ((float4*)(part + ((size_t)b * NM + e) * ND))[c * 64 + l] = acc;
            if (c == 0 && l == 0) partW[b * NM + e] = sw;
            cur = ctr[i];
            acc.x = wg[i] * xv[i].x; acc.y = wg[i] * xv[i].y;
            acc.z = wg[i] * xv[i].z; acc.w = wg[i] * xv[i].w;
            sw = wg[i];
        } else {
            acc.x += wg[i] * xv[i].x; acc.y += wg[i] * xv[i].y;
            acc.z += wg[i] * xv[i].z; acc.w += wg[i] * xv[i].w;
            sw += wg[i];
        }
    }
    int e = pos0 + 7;
    ((float4*)(part + ((size_t)b * NM + e) * ND))[c * 64 + l] = acc;
    if (c == 0 && l == 0) partW[b * NM + e] = sw;
}

// ---------------- stage B: combine segment partials, write center ----------
__global__ __launch_bounds__(256) void k_upd(
    const float* __restrict__ Cen,
    const f16* __restrict__ cenHin, const f16* __restrict__ cenLin,
    const int2* __restrict__ cb,
    const float* __restrict__ part, const float* __restrict__ partW,
    const float* __restrict__ cntFS, int iter1Mode,
    float* __restrict__ Cout, float* __restrict__ cntOut,
    f16* __restrict__ outH, f16* __restrict__ outL,
    float* __restrict__ cnP)
{
    int g = blockIdx.x * 4 + (threadIdx.x >> 6);   // 0..12287
    int lane = threadIdx.x & 63;
    int row = g / 3, c = g - row * 3;              // row = b*NK+k, chunk c
    int b = row >> 10, k = row & 1023;
    int2 cnb = cb[row];
    int n = cnb.x, base = cnb.y;
    float4 vv;
    float sumw = 0.f;
    if (n == 0) {
        if (iter1Mode) {
            vv = ((const float4*)(Cen + (size_t)row * ND))[c * 64 + lane];
            sumw = cntFS[row];
        } else {
            f16x4 hh = ((const f16x4*)(cenHin + (size_t)row * ND))[c * 64 + lane];
            f16x4 ll = ((const f16x4*)(cenLin + (size_t)row * ND))[c * 64 + lane];
            vv.x = (float)hh[0] + (float)ll[0];
            vv.y = (float)hh[1] + (float)ll[1];
            vv.z = (float)hh[2] + (float)ll[2];
            vv.w = (float)hh[3] + (float)ll[3];
            sumw = 0.f;
        }
    } else {
        float4 acc = {0.f, 0.f, 0.f, 0.f};
        int last = base + n - 1;
        int s1 = last >> 3;
        for (int s = base >> 3; s <= s1; ++s) {
            int e = (8 * s + 7 < last) ? (8 * s + 7) : last;
            float4 x = ((const float4*)(part + ((size_t)b * NM + e) * ND))[c * 64 + lane];
            acc.x += x.x; acc.y += x.y; acc.z += x.z; acc.w += x.w;
            sumw += partW[b * NM + e];
        }
        float inv = 1.0f / (sumw + 1e-8f);
        vv.x = acc.x * inv; vv.y = acc.y * inv; vv.z = acc.z * inv; vv.w = acc.w * inv;
    }
    if (!iter1Mode)
        ((float4*)(Cout + (size_t)row * ND))[c * 64 + lane] = vv;
    f16x4 h, lo;
    h[0] = (f16)vv.x; lo[0] = (f16)(vv.x - (float)h[0]);
    h[1] = (f16)vv.y; lo[1] = (f16)(vv.y - (float)h[1]);
    h[2] = (f16)vv.z; lo[2] = (f16)(vv.z - (float)h[2]);
    h[3] = (f16)vv.w; lo[3] = (f16)(vv.w - (float)h[3]);
    ((f16x4*)(outH + (size_t)row * ND))[c * 64 + lane] = h;
    ((f16x4*)(outL + (size_t)row * ND))[c * 64 + lane] = lo;
    float s2 = vv.x * vv.x + vv.y * vv.y + vv.z * vv.z + vv.w * vv.w;
#pragma unroll
    for (int off = 32; off; off >>= 1) s2 += __shfl_xor(s2, off);
    if (lane == 0) cnP[row * 3 + c] = s2;
    if (lane == 0 && c == 0) cntOut[row] = sumw;
}

// ---------------- host ----------------
extern "C" void kernel_launch(void* const* d_in, const int* in_sizes, int n_in,
                              void* d_out, int out_size, void* d_ws, size_t ws_size,
                              hipStream_t stream) {
    const float* V = (const float*)d_in[0];
    float* out = (float*)d_out;
    char* p = (char*)d_ws;
    auto take = [&](size_t bytes) { char* r = p; p += (bytes + 255) & ~(size_t)255; return r; };

    const size_t fixedBytes = 70ull * 1024 * 1024;               // ~66 MB used + slack
    const size_t fullTokBytes = 2ull * NB * NFRAMES * NN * ND * 2; // 88 MB
    const bool full = ws_size >= fixedBytes + fullTokBytes;
    const size_t tokBS = full ? (size_t)NFRAMES * NN * ND : (size_t)NN * ND; // per-batch f16 stride

    const size_t memB = (size_t)NB * NK * ND * 4;
    float* mem0 = (float*)take(memB);
    float* mem1 = (float*)take(memB);
    float* cnt0 = (float*)take(NB * NK * 4);
    float* cnt1 = (float*)take(NB * NK * 4);
    float* cntS = (float*)take(NB * NK * 4);
    float* cnP  = (float*)take(NB * NK * 3 * 4);
    unsigned long long* packed0 = (unsigned long long*)take(NB * NM * 8);
    unsigned long long* packed1 = (unsigned long long*)take(NB * NM * 8);
    int2* cbBuf  = (int2*)take(NB * NK * 8);
    int*  lstIdx = (int*)take(NB * NM * 4);
    int*  ctrOf  = (int*)take(NB * NM * 4);
    int*  totalPos = (int*)take(NB * 4);
    float* partW = (float*)take(NB * NM * 4);
    float* partB = (float*)take((size_t)NB * NM * ND * 4);
    f16* memH = (f16*)take((size_t)NB * NK * ND * 2);
    f16* memL = (f16*)take((size_t)NB * NK * ND * 2);
    f16* cenH = (f16*)take((size_t)NB * NK * ND * 2);
    f16* cenL = (f16*)take((size_t)NB * NK * ND * 2);
    f16* tokH = (f16*)take((size_t)NB * tokBS * 2);
    f16* tokL = (f16*)take((size_t)NB * tokBS * 2);

    k_init<<<1024, 256, 0, stream>>>(V, mem0, cnt0, memH, memL, cnP, packed0);
    if (full)
        k_prep<<<NB * NFRAMES * NN / 4, 256, 0, stream>>>(V, NINIT, NFRAMES, tokH, tokL, tokBS);

    float* mem[2] = {mem0, mem1};
    float* cnt[2] = {cnt0, cnt1};

    for (int f = 0; f < NFRAMES; ++f) {
        int s = f & 1, t = NINIT + f;
        float* mFS = mem[s];
        float* cFS = cnt[s];
        const f16* tH = full ? tokH + (size_t)f * NN * ND : tokH;
        const f16* tL = full ? tokL + (size_t)f * NN * ND : tokL;

        if (!full)
            k_prep<<<NB * NN / 4, 256, 0, stream>>>(V, t, 1, tokH, tokL, tokBS);

        // iter 1: score 256 new tokens vs memory; trimmed member lists.
        k_score1<<<256, 512, 0, stream>>>(tH, tL, tokBS, memH, memL, cnP, packed0);
        k_lists<<<NB, 1024, 0, stream>>>(packed0, 1, packed1, cbBuf, lstIdx, ctrOf, totalPos);
        k_part<<<480, 256, 0, stream>>>(mFS, V, t, cFS, lstIdx, ctrOf, totalPos, partB, partW);
        k_upd<<<3072, 256, 0, stream>>>(mFS, cenH, cenL, cbBuf, partB, partW, cFS, 1,
                                        out, cntS, cenH, cenL, cnP);

        // iter 2: full score (A = memory+tokens, B = tmp centers), 128x64 tiles.
        k_score2<<<640, 256, 0, stream>>>(memH, memL, tH, tL, tokBS, cenH, cenL, cnP, packed1);
        k_lists<<<NB, 1024, 0, stream>>>(packed1, 0, packed0, cbBuf, lstIdx, ctrOf, totalPos);
        k_part<<<480, 256, 0, stream>>>(mFS, V, t, cFS, lstIdx, ctrOf, totalPos, partB, partW);
        float* dst = (f == NFRAMES - 1) ? out : mem[1 - s];
        k_upd<<<3072, 256, 0, stream>>>(out, cenH, cenL, cbBuf, partB, partW, cFS, 0,
                                        dst, cnt[1 - s], memH, memL, cnP);
    }
}

// Round 12
// 2658.051 us; speedup vs baseline: 1.1845x; 1.1845x over previous
//
#include <hip/hip_runtime.h>

#define NB 4
#define NT 32
#define ND 768
#define NK 1024
#define NN 256
#define NINIT 4
#define NFRAMES 28
#define NM 1280

typedef _Float16 f16;
typedef f16 f16x8 __attribute__((ext_vector_type(8)));
typedef f16 f16x4 __attribute__((ext_vector_type(4)));
typedef float f32x4 __attribute__((ext_vector_type(4)));

#define GLOAD_LDS(g, s) __builtin_amdgcn_global_load_lds( \
    (const __attribute__((address_space(1))) void*)(g),   \
    (__attribute__((address_space(3))) void*)(s), 16, 0, 0)

// row-dependent XOR swizzle, closed within a 64-byte row (bits 4-5 only).
__device__ __forceinline__ int swz(int r) { return ((r >> 1) & 3) << 4; }

// ---------------- init: mem copy, counts=1, f16 split, cnorm partials, reset --
__global__ __launch_bounds__(256) void k_init(
    const float* __restrict__ V, float* __restrict__ mem, float* __restrict__ cnt,
    f16* __restrict__ mH, f16* __restrict__ mL,
    float* __restrict__ cnP, unsigned long long* __restrict__ packed0,
    int* __restrict__ scoreIdxTok)
{
    int gid = blockIdx.x * 256 + threadIdx.x;
    if (gid < NB * 512) {                      // constant iter1 score index list
        int i = gid & 511;
        scoreIdxTok[gid] = (i < 256) ? NK + i : -1;
    }
    int row = blockIdx.x * 4 + (threadIdx.x >> 6);   // 0..4095
    int lane = threadIdx.x & 63;
    int b = row >> 10, k = row & 1023;
    const float4* src = (const float4*)(V + ((size_t)b * NT * NN + k) * ND);
    float4* mrow = (float4*)(mem + (size_t)row * ND);
    f16x4* hrow = (f16x4*)(mH + (size_t)row * ND);
    f16x4* lrow = (f16x4*)(mL + (size_t)row * ND);
    float s2 = 0.f;
#pragma unroll
    for (int jj = 0; jj < 3; ++jj) {
        float4 x = src[lane + 64 * jj];
        mrow[lane + 64 * jj] = x;
        f16x4 h, lo;
        h[0] = (f16)x.x; lo[0] = (f16)(x.x - (float)h[0]);
        h[1] = (f16)x.y; lo[1] = (f16)(x.y - (float)h[1]);
        h[2] = (f16)x.z; lo[2] = (f16)(x.z - (float)h[2]);
        h[3] = (f16)x.w; lo[3] = (f16)(x.w - (float)h[3]);
        hrow[lane + 64 * jj] = h;
        lrow[lane + 64 * jj] = lo;
        s2 += x.x * x.x + x.y * x.y + x.z * x.z + x.w * x.w;
    }
#pragma unroll
    for (int off = 32; off; off >>= 1) s2 += __shfl_xor(s2, off);
    if (lane == 0) {
        cnP[row * 3] = s2; cnP[row * 3 + 1] = 0.f; cnP[row * 3 + 2] = 0.f;
        cnt[row] = 1.0f; packed0[(size_t)b * NM + k] = ~0ull;
    }
    if (lane == 1 && k < NN) packed0[(size_t)b * NM + NK + k] = ~0ull;
}

// ---------------- token split: frames t0..t0+nF-1 -> slots 0..nF-1 ----------
__global__ __launch_bounds__(256) void k_prep(
    const float* __restrict__ V, int t0, int nF,
    f16* __restrict__ tokH, f16* __restrict__ tokL, size_t tokBS)
{
    int g = blockIdx.x * 4 + (threadIdx.x >> 6);
    int lane = threadIdx.x & 63;
    int perB = nF * NN;
    if (g >= NB * perB) return;
    int b = g / perB;
    int rem = g - b * perB;
    int fi = rem / NN, n = rem - fi * NN;
    const float4* src = (const float4*)(V + (((size_t)b * NT + t0 + fi) * NN + n) * ND);
    f16x4* hrow = (f16x4*)(tokH + (size_t)b * tokBS + (size_t)(fi * NN + n) * ND);
    f16x4* lrow = (f16x4*)(tokL + (size_t)b * tokBS + (size_t)(fi * NN + n) * ND);
#pragma unroll
    for (int jj = 0; jj < 3; ++jj) {
        float4 x = src[lane + 64 * jj];
        f16x4 h, lo;
        h[0] = (f16)x.x; lo[0] = (f16)(x.x - (float)h[0]);
        h[1] = (f16)x.y; lo[1] = (f16)(x.y - (float)h[1]);
        h[2] = (f16)x.z; lo[2] = (f16)(x.z - (float)h[2]);
        h[3] = (f16)x.w; lo[3] = (f16)(x.w - (float)h[3]);
        hrow[lane + 64 * jj] = h;
        lrow[lane + 64 * jj] = lo;
    }
}

// -------- index-gathered MFMA score: MT=64 split-D 8-wave blocks ------------
// A rows come from sidx[b][0..511] (mem row id <NK, token id >=NK, -1 = pad).
// B = 1024 center rows (BH/BL). grid = NB * mTiles * 16 blocks x 512 threads.
__global__ __launch_bounds__(512) void k_scoreX(
    const int* __restrict__ sidx, int mTiles,
    const f16* __restrict__ MH, const f16* __restrict__ ML,
    const f16* __restrict__ TH, const f16* __restrict__ TL, size_t tokBS,
    const f16* __restrict__ BH, const f16* __restrict__ BL,
    const float* __restrict__ cnP,
    unsigned long long* __restrict__ packed)
{
    constexpr int MT = 64;
    constexpr int FM = 2;
    constexpr int QROWS = 32;
    constexpr int ASL = 4;
    constexpr int SLOTS = 16;
    constexpr int SPW = 4;
    constexpr int RSZ = SLOTS * 1024;

    __shared__ float4 ldsbuf[SLOTS * 128];   // 32 KB: 2 D-half regions x 16 KB
    char* lds = (char*)ldsbuf;

    int bid = blockIdx.x;
    int cpx = (int)gridDim.x >> 3;
    int sz = (bid & 7) * cpx + (bid >> 3);   // XCD-aware (grid % 8 == 0)
    int pb = mTiles * 16;
    int b = sz / pb;
    int rem = sz - b * pb;
    int mt = rem >> 4, kt = rem & 15;
    int tid = threadIdx.x;
    int w = tid >> 6, l = tid & 63;
    int h = w >> 2, q = w & 3;
    int wm = q >> 1, wk = q & 1;
    const int REG = h * RSZ;
    const int* sb = sidx + b * 512;

    const char* sp[SPW];
#pragma unroll
    for (int i = 0; i < SPW; ++i) {
        int slot = q * SPW + i;
        const f16* base; int r;
        if (slot < ASL) {
            r = slot * 16 + (l >> 2);
            int rid = sb[mt * MT + r]; if (rid < 0) rid = 0;
            base = (rid < NK) ? MH + ((size_t)b * NK + rid) * ND
                              : TH + (size_t)b * tokBS + (size_t)(rid - NK) * ND;
        } else if (slot < 2 * ASL) {
            r = (slot - ASL) * 16 + (l >> 2);
            int rid = sb[mt * MT + r]; if (rid < 0) rid = 0;
            base = (rid < NK) ? ML + ((size_t)b * NK + rid) * ND
                              : TL + (size_t)b * tokBS + (size_t)(rid - NK) * ND;
        } else if (slot < 2 * ASL + 4) {
            r = (slot - 2 * ASL) * 16 + (l >> 2);
            base = BH + ((size_t)b * NK + kt * 64 + r) * ND;
        } else {
            r = (slot - 2 * ASL - 4) * 16 + (l >> 2);
            base = BL + ((size_t)b * NK + kt * 64 + r) * ND;
        }
        int colB = ((l & 3) * 16) ^ swz(r);
        sp[i] = (const char*)base + h * 768 + colB;
    }

    int aoffH[FM], aoffL[FM], boffH[2], boffL[2];
#pragma unroll
    for (int mi = 0; mi < FM; ++mi) {
        int r = wm * QROWS + mi * 16 + (l & 15);
        int off = r * 64 + (((l >> 4) * 16) ^ swz(r));
        aoffH[mi] = REG + off;
        aoffL[mi] = REG + ASL * 1024 + off;
    }
#pragma unroll
    for (int nj = 0; nj < 2; ++nj) {
        int rB = wk * 32 + nj * 16 + (l & 15);
        int off = rB * 64 + (((l >> 4) * 16) ^ swz(rB));
        boffH[nj] = REG + 2 * ASL * 1024 + off;
        boffL[nj] = REG + 2 * ASL * 1024 + 4096 + off;
    }

    f32x4 acc[FM][2] = {};

    for (int c = 0; c < 12; ++c) {
#pragma unroll
        for (int i = 0; i < SPW; ++i) {
            GLOAD_LDS(sp[i], lds + REG + (q * SPW + i) * 1024);
            sp[i] += 64;
        }
        __syncthreads();
        f16x8 ah[FM], al[FM], bh[2], bl[2];
#pragma unroll
        for (int mi = 0; mi < FM; ++mi) {
            ah[mi] = *(const f16x8*)(lds + aoffH[mi]);
            al[mi] = *(const f16x8*)(lds + aoffL[mi]);
        }
#pragma unroll
        for (int nj = 0; nj < 2; ++nj) {
            bh[nj] = *(const f16x8*)(lds + boffH[nj]);
            bl[nj] = *(const f16x8*)(lds + boffL[nj]);
        }
#pragma unroll
        for (int mi = 0; mi < FM; ++mi)
#pragma unroll
            for (int nj = 0; nj < 2; ++nj) {
                acc[mi][nj] = __builtin_amdgcn_mfma_f32_16x16x32_f16(ah[mi], bh[nj], acc[mi][nj], 0, 0, 0);
                acc[mi][nj] = __builtin_amdgcn_mfma_f32_16x16x32_f16(ah[mi], bl[nj], acc[mi][nj], 0, 0, 0);
                acc[mi][nj] = __builtin_amdgcn_mfma_f32_16x16x32_f16(al[mi], bh[nj], acc[mi][nj], 0, 0, 0);
            }
        __syncthreads();
    }

    int coff = q * (QROWS * 128) + l * 16;
    if (h == 1) {
#pragma unroll
        for (int mi = 0; mi < FM; ++mi)
#pragma unroll
            for (int nj = 0; nj < 2; ++nj)
                *(f32x4*)(lds + coff + (mi * 2 + nj) * 1024) = acc[mi][nj];
    }
    __syncthreads();
    if (h != 0) return;
#pragma unroll
    for (int mi = 0; mi < FM; ++mi)
#pragma unroll
        for (int nj = 0; nj < 2; ++nj)
            acc[mi][nj] += *(const f32x4*)(lds + coff + (mi * 2 + nj) * 1024);

    int colb = kt * 64 + wk * 32 + (l & 15);
    float cn[2];
#pragma unroll
    for (int nj = 0; nj < 2; ++nj) {
        int kc = b * NK + colb + nj * 16;
        cn[nj] = cnP[kc * 3] + cnP[kc * 3 + 1] + cnP[kc * 3 + 2];
    }
    size_t pbase = (size_t)b * NM;
#pragma unroll
    for (int mi = 0; mi < FM; ++mi) {
#pragma unroll
        for (int rg = 0; rg < 4; ++rg) {
            float bv = 1e30f; int bi = 0;
#pragma unroll
            for (int nj = 0; nj < 2; ++nj) {
                float s = cn[nj] - 2.0f * acc[mi][nj][rg];
                int ki = colb + nj * 16;
                if (s < bv) { bv = s; bi = ki; }
            }
#pragma unroll
            for (int off = 1; off < 16; off <<= 1) {
                float ov = __shfl_xor(bv, off);
                int   oi = __shfl_xor(bi, off);
                if (ov < bv || (ov == bv && oi < bi)) { bv = ov; bi = oi; }
            }
            if ((l & 15) == 0) {
                int Rt = mt * MT + wm * QROWS + mi * 16 + (l >> 4) * 4 + rg;
                int rid = sb[Rt];
                if (rid >= 0) {
                    unsigned u = __float_as_uint(bv);
                    unsigned key = (u >> 31) ? ~u : (u | 0x80000000u);
                    atomicMin(&packed[pbase + rid],
                              ((unsigned long long)key << 32) | (unsigned)bi);
                }
            }
        }
    }
}

// ---------------- build CSR lists; iter1 also emits iter2 score list --------
__global__ __launch_bounds__(1024) void k_lists(
    const unsigned long long* __restrict__ packed, int selfSeed,
    unsigned long long* __restrict__ packedOther,
    int2* __restrict__ cb, int* __restrict__ lstIdx, int* __restrict__ ctrOf,
    int* __restrict__ totalPos, int* __restrict__ scoreIdx2)
{
    __shared__ int cntL[NK];
    __shared__ int wsum[16];
    __shared__ int hwsum[16];
    __shared__ int cursor[NK];
    __shared__ int aSh[NM];
    __shared__ int totSh, hitSh;
    int b = blockIdx.x, tid = threadIdx.x;
    cntL[tid] = 0;
    __syncthreads();
    if (selfSeed) {
        if (tid < NN) {
            int a = (int)(unsigned)(packed[(size_t)b * NM + NK + tid] & 0xffffffffull);
            aSh[tid] = a;
            atomicAdd(&cntL[a], 1);
        }
    } else {
        for (int m = tid; m < NM; m += 1024) {
            int a = (int)(unsigned)(packed[(size_t)b * NM + m] & 0xffffffffull);
            aSh[m] = a;
            atomicAdd(&cntL[a], 1);
            packedOther[(size_t)b * NM + m] = ~0ull;
        }
    }
    __syncthreads();
    int v0 = cntL[tid];
    int v = selfSeed ? (v0 ? v0 + 1 : 0) : v0;
    int hit = (selfSeed && v0 > 0) ? 1 : 0;
    int lane = tid & 63, wv = tid >> 6;
    int x = v, hx = hit;
#pragma unroll
    for (int off = 1; off < 64; off <<= 1) {
        int y = __shfl_up(x, off);
        int hy = __shfl_up(hx, off);
        if (lane >= off) { x += y; hx += hy; }
    }
    if (lane == 63) { wsum[wv] = x; hwsum[wv] = hx; }
    __syncthreads();
    if (tid < 16) {
        int s = wsum[tid];
        int e = s;
#pragma unroll
        for (int off = 1; off < 16; off <<= 1) {
            int y = __shfl_up(e, off, 16);
            if (tid >= off) e += y;
        }
        wsum[tid] = e - s;
    } else if (tid < 32) {
        int s = hwsum[tid - 16];
        int e = s;
#pragma unroll
        for (int off = 1; off < 16; off <<= 1) {
            int y = __shfl_up(e, off, 16);
            if ((tid - 16) >= off) e += y;
        }
        hwsum[tid - 16] = e - s;
    }
    __syncthreads();
    int base = x + wsum[wv] - v;               // exclusive prefix of v
    int hb = hx + hwsum[wv] - hit;             // exclusive prefix of hits
    cursor[tid] = base + ((selfSeed && v0) ? 1 : 0);
    cb[b * NK + tid] = make_int2(v, base);
    if (selfSeed && v0) {                      // self entry first (row = tid)
        lstIdx[(size_t)b * NM + base] = tid;
        ctrOf[(size_t)b * NM + base] = tid;
    }
    if (selfSeed) {
        packedOther[(size_t)b * NM + tid] = hit ? ~0ull : (unsigned long long)(unsigned)tid;
        if (tid < NN) packedOther[(size_t)b * NM + NK + tid] = ~0ull;
        if (hit) scoreIdx2[b * 512 + 256 + hb] = tid;
        if (tid < 256) scoreIdx2[b * 512 + tid] = NK + tid;
        if (tid == 1023) hitSh = hb + hit;
    }
    if (tid == 1023) totSh = base + v;
    __syncthreads();
    if (selfSeed) {
        if (tid < NN) {
            int a = aSh[tid];
            int pos = atomicAdd(&cursor[a], 1);
            lstIdx[(size_t)b * NM + pos] = NK + tid;
            ctrOf[(size_t)b * NM + pos] = a;
        }
        int H = hitSh;
        if (tid >= H && tid < 256) scoreIdx2[b * 512 + 256 + tid] = -1;
        if (tid == 0) {
            int total = totSh;
            int padEnd = (total + 7) & ~7;
            for (int p2 = total; p2 < padEnd; ++p2) {
                lstIdx[(size_t)b * NM + p2] = 0;
                ctrOf[(size_t)b * NM + p2] = -1;
            }
            totalPos[b] = total;
        }
    } else {
        for (int m = tid; m < NM; m += 1024) {
            int a = aSh[m];
            int pos = atomicAdd(&cursor[a], 1);
            lstIdx[(size_t)b * NM + pos] = m;
            ctrOf[(size_t)b * NM + pos] = a;
        }
        if (tid == 0) totalPos[b] = NM;
    }
}

// ---------------- stage A: per-8-position segment partial sums --------------
__global__ __launch_bounds__(256) void k_part(
    const float* __restrict__ memFS, const float* __restrict__ V, int t,
    const float* __restrict__ cntFS,
    const int* __restrict__ lstIdx, const int* __restrict__ ctrOf,
    const int* __restrict__ totalPos,
    float* __restrict__ part, float* __restrict__ partW)
{
    int g = blockIdx.x * 4 + (threadIdx.x >> 6);   // 0..1919
    int l = threadIdx.x & 63;
    int b = g / 480;
    int rem = g - b * 480;
    int seg = rem / 3, c = rem - seg * 3;
    int pos0 = seg * 8;
    if (pos0 >= totalPos[b]) return;
    const int* li = lstIdx + (size_t)b * NM;
    const int* co = ctrOf + (size_t)b * NM;
    int ctr[8]; float wg[8]; float4 xv[8];
#pragma unroll
    for (int i = 0; i < 8; ++i) {
        int p = pos0 + i;
        int cc = co[p];
        int mm = li[p];
        bool pad = cc < 0;
        ctr[i] = pad ? -2 : cc;
        wg[i] = pad ? 0.f : ((mm < NK) ? cntFS[b * NK + mm] : 1.0f);
        int mload = pad ? 0 : mm;
        const float4* dr = (mload < NK)
            ? (const float4*)(memFS + ((size_t)b * NK + mload) * ND)
            : (const float4*)(V + (((size_t)b * NT + t) * NN + (mload - NK)) * (size_t)ND);
        xv[i] = dr[c * 64 + l];
    }
    float4 acc; float sw; int cur = ctr[0];
    acc.x = wg[0] * xv[0].x; acc.y = wg[0] * xv[0].y;
    acc.z = wg[0] * xv[0].z; acc.w = wg[0] * xv[0].w;
    sw = wg[0];
#pragma unroll
    for (int i = 1; i < 8; ++i) {
        if (ctr[i] != cur) {
            int e = pos0 + i - 1;
            ((float4*)(part + ((size_t)b * NM + e) * ND))[c * 64 + l] = acc;
            if (c == 0 && l == 0) partW[b * NM + e] = sw;
            cur = ctr[i];
            acc.x = wg[i] * xv[i].x; acc.y = wg[i] * xv[i].y;
            acc.z = wg[i] * xv[i].z; acc.w = wg[i] * xv[i].w;
            sw = wg[i];
        } else {
            acc.x += wg[i] * xv[i].x; acc.y += wg[i] * xv[i].y;
            acc.z += wg[i] * xv[i].z; acc.w += wg[i] * xv[i].w;
            sw += wg[i];
        }
    }
    int e = pos0 + 7;
    ((float4*)(part + ((size_t)b * NM + e) * ND))[c * 64 + l] = acc;
    if (c == 0 && l == 0) partW[b * NM + e] = sw;
}

// ---------------- stage B: combine segment partials, write center ----------
__global__ __launch_bounds__(256) void k_upd(
    const float* __restrict__ Cen,
    const f16* __restrict__ cenHin, const f16* __restrict__ cenLin,
    const int2* __restrict__ cb,
    const float* __restrict__ part, const float* __restrict__ partW,
    const float* __restrict__ cntFS, int iter1Mode,
    float* __restrict__ Cout, float* __restrict__ cntOut,
    f16* __restrict__ outH, f16* __restrict__ outL,
    float* __restrict__ cnP)
{
    int g = blockIdx.x * 4 + (threadIdx.x >> 6);   // 0..12287
    int lane = threadIdx.x & 63;
    int row = g / 3, c = g - row * 3;              // row = b*NK+k, chunk c
    int b = row >> 10, k = row & 1023;
    int2 cnb = cb[row];
    int n = cnb.x, base = cnb.y;
    float4 vv;
    float sumw = 0.f;
    if (n == 0) {
        if (iter1Mode) {
            vv = ((const float4*)(Cen + (size_t)row * ND))[c * 64 + lane];
            sumw = cntFS[row];
        } else {
            f16x4 hh = ((const f16x4*)(cenHin + (size_t)row * ND))[c * 64 + lane];
            f16x4 ll = ((const f16x4*)(cenLin + (size_t)row * ND))[c * 64 + lane];
            vv.x = (float)hh[0] + (float)ll[0];
            vv.y = (float)hh[1] + (float)ll[1];
            vv.z = (float)hh[2] + (float)ll[2];
            vv.w = (float)hh[3] + (float)ll[3];
            sumw = 0.f;
        }
    } else {
        float4 acc = {0.f, 0.f, 0.f, 0.f};
        int last = base + n - 1;
        int s1 = last >> 3;
        for (int s = base >> 3; s <= s1; ++s) {
            int e = (8 * s + 7 < last) ? (8 * s + 7) : last;
            float4 x = ((const float4*)(part + ((size_t)b * NM + e) * ND))[c * 64 + lane];
            acc.x += x.x; acc.y += x.y; acc.z += x.z; acc.w += x.w;
            sumw += partW[b * NM + e];
        }
        float inv = 1.0f / (sumw + 1e-8f);
        vv.x = acc.x * inv; vv.y = acc.y * inv; vv.z = acc.z * inv; vv.w = acc.w * inv;
    }
    if (!iter1Mode)
        ((float4*)(Cout + (size_t)row * ND))[c * 64 + lane] = vv;
    f16x4 h, lo;
    h[0] = (f16)vv.x; lo[0] = (f16)(vv.x - (float)h[0]);
    h[1] = (f16)vv.y; lo[1] = (f16)(vv.y - (float)h[1]);
    h[2] = (f16)vv.z; lo[2] = (f16)(vv.z - (float)h[2]);
    h[3] = (f16)vv.w; lo[3] = (f16)(vv.w - (float)h[3]);
    ((f16x4*)(outH + (size_t)row * ND))[c * 64 + lane] = h;
    ((f16x4*)(outL + (size_t)row * ND))[c * 64 + lane] = lo;
    float s2 = vv.x * vv.x + vv.y * vv.y + vv.z * vv.z + vv.w * vv.w;
#pragma unroll
    for (int off = 32; off; off >>= 1) s2 += __shfl_xor(s2, off);
    if (lane == 0) cnP[row * 3 + c] = s2;
    if (lane == 0 && c == 0) cntOut[row] = sumw;
}

// ---------------- host ----------------
extern "C" void kernel_launch(void* const* d_in, const int* in_sizes, int n_in,
                              void* d_out, int out_size, void* d_ws, size_t ws_size,
                              hipStream_t stream) {
    const float* V = (const float*)d_in[0];
    float* out = (float*)d_out;
    char* p = (char*)d_ws;
    auto take = [&](size_t bytes) { char* r = p; p += (bytes + 255) & ~(size_t)255; return r; };

    const size_t fixedBytes = 70ull * 1024 * 1024;
    const size_t fullTokBytes = 2ull * NB * NFRAMES * NN * ND * 2;
    const bool full = ws_size >= fixedBytes + fullTokBytes;
    const size_t tokBS = full ? (size_t)NFRAMES * NN * ND : (size_t)NN * ND;

    const size_t memB = (size_t)NB * NK * ND * 4;
    float* mem0 = (float*)take(memB);
    float* mem1 = (float*)take(memB);
    float* cnt0 = (float*)take(NB * NK * 4);
    float* cnt1 = (float*)take(NB * NK * 4);
    float* cntS = (float*)take(NB * NK * 4);
    float* cnP  = (float*)take(NB * NK * 3 * 4);
    unsigned long long* packed0 = (unsigned long long*)take(NB * NM * 8);
    unsigned long long* packed1 = (unsigned long long*)take(NB * NM * 8);
    int2* cbBuf  = (int2*)take(NB * NK * 8);
    int*  lstIdx = (int*)take(NB * NM * 4);
    int*  ctrOf  = (int*)take(NB * NM * 4);
    int*  totalPos = (int*)take(NB * 4);
    int*  scoreIdxTok = (int*)take(NB * 512 * 4);
    int*  scoreIdx2   = (int*)take(NB * 512 * 4);
    float* partW = (float*)take(NB * NM * 4);
    float* partB = (float*)take((size_t)NB * NM * ND * 4);
    f16* memH = (f16*)take((size_t)NB * NK * ND * 2);
    f16* memL = (f16*)take((size_t)NB * NK * ND * 2);
    f16* cenH = (f16*)take((size_t)NB * NK * ND * 2);
    f16* cenL = (f16*)take((size_t)NB * NK * ND * 2);
    f16* tokH = (f16*)take((size_t)NB * tokBS * 2);
    f16* tokL = (f16*)take((size_t)NB * tokBS * 2);

    k_init<<<1024, 256, 0, stream>>>(V, mem0, cnt0, memH, memL, cnP, packed0, scoreIdxTok);
    if (full)
        k_prep<<<NB * NFRAMES * NN / 4, 256, 0, stream>>>(V, NINIT, NFRAMES, tokH, tokL, tokBS);

    float* mem[2] = {mem0, mem1};
    float* cnt[2] = {cnt0, cnt1};

    for (int f = 0; f < NFRAMES; ++f) {
        int s = f & 1, t = NINIT + f;
        float* mFS = mem[s];
        float* cFS = cnt[s];
        const f16* tH = full ? tokH + (size_t)f * NN * ND : tokH;
        const f16* tL = full ? tokL + (size_t)f * NN * ND : tokL;

        if (!full)
            k_prep<<<NB * NN / 4, 256, 0, stream>>>(V, t, 1, tokH, tokL, tokBS);

        // iter 1: score 256 tokens vs memory centers (M=256, 4 mTiles).
        k_scoreX<<<256, 512, 0, stream>>>(scoreIdxTok, 4, memH, memL, tH, tL, tokBS,
                                          memH, memL, cnP, packed0);
        k_lists<<<NB, 1024, 0, stream>>>(packed0, 1, packed1, cbBuf, lstIdx, ctrOf,
                                         totalPos, scoreIdx2);
        k_part<<<480, 256, 0, stream>>>(mFS, V, t, cFS, lstIdx, ctrOf, totalPos, partB, partW);
        k_upd<<<3072, 256, 0, stream>>>(mFS, cenH, cenL, cbBuf, partB, partW, cFS, 1,
                                        out, cntS, cenH, cenL, cnP);

        // iter 2: score only tokens + hit rows (M<=512, 8 mTiles) vs new centers;
        // unhit memory rows provably self-assign (pre-written in packed1).
        k_scoreX<<<512, 512, 0, stream>>>(scoreIdx2, 8, memH, memL, tH, tL, tokBS,
                                          cenH, cenL, cnP, packed1);
        k_lists<<<NB, 1024, 0, stream>>>(packed1, 0, packed0, cbBuf, lstIdx, ctrOf,
                                         totalPos, scoreIdx2);
        k_part<<<480, 256, 0, stream>>>(mFS, V, t, cFS, lstIdx, ctrOf, totalPos, partB, partW);
        float* dst = (f == NFRAMES - 1) ? out : mem[1 - s];
        k_upd<<<3072, 256, 0, stream>>>(out, cenH, cenL, cbBuf, partB, partW, cFS, 0,
                                        dst, cnt[1 - s], memH, memL, cnP);
    }
}

// Round 14
// 2553.913 us; speedup vs baseline: 1.2328x; 1.0408x over previous
//
#include <hip/hip_runtime.h>

#define NB 4
#define NT 32
#define ND 768
#define NK 1024
#define NN 256
#define NINIT 4
#define NFRAMES 28
#define NM 1280

typedef _Float16 f16;
typedef f16 f16x8 __attribute__((ext_vector_type(8)));
typedef f16 f16x4 __attribute__((ext_vector_type(4)));
typedef float f32x4 __attribute__((ext_vector_type(4)));

#define GLOAD_LDS(g, s) __builtin_amdgcn_global_load_lds( \
    (const __attribute__((address_space(1))) void*)(g),   \
    (__attribute__((address_space(3))) void*)(s), 16, 0, 0)

// row-dependent XOR swizzle, closed within a 64-byte row (bits 4-5 only).
__device__ __forceinline__ int swz(int r) { return ((r >> 1) & 3) << 4; }

// ---------------- init: mem copy, counts=1, f16 split, cnorm partials, reset --
__global__ __launch_bounds__(256) void k_init(
    const float* __restrict__ V, float* __restrict__ memF, float* __restrict__ cnt,
    f16* __restrict__ mH, f16* __restrict__ mL,
    float* __restrict__ cnP, unsigned long long* __restrict__ packed0,
    int* __restrict__ scoreIdxTok)
{
    int gid = blockIdx.x * 256 + threadIdx.x;
    if (gid < NB * 512) {                      // constant iter1 score index list
        int i = gid & 511;
        scoreIdxTok[gid] = (i < 256) ? NK + i : -1;
    }
    int row = blockIdx.x * 4 + (threadIdx.x >> 6);   // 0..4095
    int lane = threadIdx.x & 63;
    int b = row >> 10, k = row & 1023;
    const float4* src = (const float4*)(V + ((size_t)b * NT * NN + k) * ND);
    float4* mrow = (float4*)(memF + (size_t)row * ND);
    f16x4* hrow = (f16x4*)(mH + (size_t)row * ND);
    f16x4* lrow = (f16x4*)(mL + (size_t)row * ND);
    float s2 = 0.f;
#pragma unroll
    for (int jj = 0; jj < 3; ++jj) {
        float4 x = src[lane + 64 * jj];
        mrow[lane + 64 * jj] = x;
        f16x4 h, lo;
        h[0] = (f16)x.x; lo[0] = (f16)(x.x - (float)h[0]);
        h[1] = (f16)x.y; lo[1] = (f16)(x.y - (float)h[1]);
        h[2] = (f16)x.z; lo[2] = (f16)(x.z - (float)h[2]);
        h[3] = (f16)x.w; lo[3] = (f16)(x.w - (float)h[3]);
        hrow[lane + 64 * jj] = h;
        lrow[lane + 64 * jj] = lo;
        s2 += x.x * x.x + x.y * x.y + x.z * x.z + x.w * x.w;
    }
#pragma unroll
    for (int off = 32; off; off >>= 1) s2 += __shfl_xor(s2, off);
    if (lane == 0) {
        cnP[row * 3] = s2; cnP[row * 3 + 1] = 0.f; cnP[row * 3 + 2] = 0.f;
        cnt[row] = 1.0f; packed0[(size_t)b * NM + k] = ~0ull;
    }
    if (lane == 1 && k < NN) packed0[(size_t)b * NM + NK + k] = ~0ull;
}

// ---------------- token split: frames t0..t0+nF-1 -> slots 0..nF-1 ----------
__global__ __launch_bounds__(256) void k_prep(
    const float* __restrict__ V, int t0, int nF,
    f16* __restrict__ tokH, f16* __restrict__ tokL, size_t tokBS)
{
    int g = blockIdx.x * 4 + (threadIdx.x >> 6);
    int lane = threadIdx.x & 63;
    int perB = nF * NN;
    if (g >= NB * perB) return;
    int b = g / perB;
    int rem = g - b * perB;
    int fi = rem / NN, n = rem - fi * NN;
    const float4* src = (const float4*)(V + (((size_t)b * NT + t0 + fi) * NN + n) * ND);
    f16x4* hrow = (f16x4*)(tokH + (size_t)b * tokBS + (size_t)(fi * NN + n) * ND);
    f16x4* lrow = (f16x4*)(tokL + (size_t)b * tokBS + (size_t)(fi * NN + n) * ND);
#pragma unroll
    for (int jj = 0; jj < 3; ++jj) {
        float4 x = src[lane + 64 * jj];
        f16x4 h, lo;
        h[0] = (f16)x.x; lo[0] = (f16)(x.x - (float)h[0]);
        h[1] = (f16)x.y; lo[1] = (f16)(x.y - (float)h[1]);
        h[2] = (f16)x.z; lo[2] = (f16)(x.z - (float)h[2]);
        h[3] = (f16)x.w; lo[3] = (f16)(x.w - (float)h[3]);
        hrow[lane + 64 * jj] = h;
        lrow[lane + 64 * jj] = lo;
    }
}

// -------- index-gathered MFMA score: MT=64 split-D 8-wave blocks ------------
// A rows come from sidx[b][0..511] (mem row id <NK, token id >=NK, -1 = pad).
// B = 1024 center rows (BH/BL). grid = NB * mTiles * 16 blocks x 512 threads.
__global__ __launch_bounds__(512) void k_scoreX(
    const int* __restrict__ sidx, int mTiles,
    const f16* __restrict__ MH, const f16* __restrict__ ML,
    const f16* __restrict__ TH, const f16* __restrict__ TL, size_t tokBS,
    const f16* __restrict__ BH, const f16* __restrict__ BL,
    const float* __restrict__ cnP,
    unsigned long long* __restrict__ packed)
{
    constexpr int MT = 64;
    constexpr int FM = 2;
    constexpr int QROWS = 32;
    constexpr int ASL = 4;
    constexpr int SLOTS = 16;
    constexpr int SPW = 4;
    constexpr int RSZ = SLOTS * 1024;

    __shared__ float4 ldsbuf[SLOTS * 128];   // 32 KB: 2 D-half regions x 16 KB
    char* lds = (char*)ldsbuf;

    int bid = blockIdx.x;
    int cpx = (int)gridDim.x >> 3;
    int sz = (bid & 7) * cpx + (bid >> 3);   // XCD-aware (grid % 8 == 0)
    int pb = mTiles * 16;
    int b = sz / pb;
    int rem = sz - b * pb;
    int mt = rem >> 4, kt = rem & 15;
    int tid = threadIdx.x;
    int w = tid >> 6, l = tid & 63;
    int h = w >> 2, q = w & 3;
    int wm = q >> 1, wk = q & 1;
    const int REG = h * RSZ;
    const int* sb = sidx + b * 512;

    const char* sp[SPW];
#pragma unroll
    for (int i = 0; i < SPW; ++i) {
        int slot = q * SPW + i;
        const f16* base; int r;
        if (slot < ASL) {
            r = slot * 16 + (l >> 2);
            int rid = sb[mt * MT + r]; if (rid < 0) rid = 0;
            base = (rid < NK) ? MH + ((size_t)b * NK + rid) * ND
                              : TH + (size_t)b * tokBS + (size_t)(rid - NK) * ND;
        } else if (slot < 2 * ASL) {
            r = (slot - ASL) * 16 + (l >> 2);
            int rid = sb[mt * MT + r]; if (rid < 0) rid = 0;
            base = (rid < NK) ? ML + ((size_t)b * NK + rid) * ND
                              : TL + (size_t)b * tokBS + (size_t)(rid - NK) * ND;
        } else if (slot < 2 * ASL + 4) {
            r = (slot - 2 * ASL) * 16 + (l >> 2);
            base = BH + ((size_t)b * NK + kt * 64 + r) * ND;
        } else {
            r = (slot - 2 * ASL - 4) * 16 + (l >> 2);
            base = BL + ((size_t)b * NK + kt * 64 + r) * ND;
        }
        int colB = ((l & 3) * 16) ^ swz(r);
        sp[i] = (const char*)base + h * 768 + colB;
    }

    int aoffH[FM], aoffL[FM], boffH[2], boffL[2];
#pragma unroll
    for (int mi = 0; mi < FM; ++mi) {
        int r = wm * QROWS + mi * 16 + (l & 15);
        int off = r * 64 + (((l >> 4) * 16) ^ swz(r));
        aoffH[mi] = REG + off;
        aoffL[mi] = REG + ASL * 1024 + off;
    }
#pragma unroll
    for (int nj = 0; nj < 2; ++nj) {
        int rB = wk * 32 + nj * 16 + (l & 15);
        int off = rB * 64 + (((l >> 4) * 16) ^ swz(rB));
        boffH[nj] = REG + 2 * ASL * 1024 + off;
        boffL[nj] = REG + 2 * ASL * 1024 + 4096 + off;
    }

    f32x4 acc[FM][2] = {};

    for (int c = 0; c < 12; ++c) {
#pragma unroll
        for (int i = 0; i < SPW; ++i) {
            GLOAD_LDS(sp[i], lds + REG + (q * SPW + i) * 1024);
            sp[i] += 64;
        }
        __syncthreads();
        f16x8 ah[FM], al[FM], bh[2], bl[2];
#pragma unroll
        for (int mi = 0; mi < FM; ++mi) {
            ah[mi] = *(const f16x8*)(lds + aoffH[mi]);
            al[mi] = *(const f16x8*)(lds + aoffL[mi]);
        }
#pragma unroll
        for (int nj = 0; nj < 2; ++nj) {
            bh[nj] = *(const f16x8*)(lds + boffH[nj]);
            bl[nj] = *(const f16x8*)(lds + boffL[nj]);
        }
#pragma unroll
        for (int mi = 0; mi < FM; ++mi)
#pragma unroll
            for (int nj = 0; nj < 2; ++nj) {
                acc[mi][nj] = __builtin_amdgcn_mfma_f32_16x16x32_f16(ah[mi], bh[nj], acc[mi][nj], 0, 0, 0);
                acc[mi][nj] = __builtin_amdgcn_mfma_f32_16x16x32_f16(ah[mi], bl[nj], acc[mi][nj], 0, 0, 0);
                acc[mi][nj] = __builtin_amdgcn_mfma_f32_16x16x32_f16(al[mi], bh[nj], acc[mi][nj], 0, 0, 0);
            }
        __syncthreads();
    }

    int coff = q * (QROWS * 128) + l * 16;
    if (h == 1) {
#pragma unroll
        for (int mi = 0; mi < FM; ++mi)
#pragma unroll
            for (int nj = 0; nj < 2; ++nj)
                *(f32x4*)(lds + coff + (mi * 2 + nj) * 1024) = acc[mi][nj];
    }
    __syncthreads();
    if (h != 0) return;
#pragma unroll
    for (int mi = 0; mi < FM; ++mi)
#pragma unroll
        for (int nj = 0; nj < 2; ++nj)
            acc[mi][nj] += *(const f32x4*)(lds + coff + (mi * 2 + nj) * 1024);

    int colb = kt * 64 + wk * 32 + (l & 15);
    float cn[2];
#pragma unroll
    for (int nj = 0; nj < 2; ++nj) {
        int kc = b * NK + colb + nj * 16;
        cn[nj] = cnP[kc * 3] + cnP[kc * 3 + 1] + cnP[kc * 3 + 2];
    }
    size_t pbase = (size_t)b * NM;
#pragma unroll
    for (int mi = 0; mi < FM; ++mi) {
#pragma unroll
        for (int rg = 0; rg < 4; ++rg) {
            float bv = 1e30f; int bi = 0;
#pragma unroll
            for (int nj = 0; nj < 2; ++nj) {
                float s = cn[nj] - 2.0f * acc[mi][nj][rg];
                int ki = colb + nj * 16;
                if (s < bv) { bv = s; bi = ki; }
            }
#pragma unroll
            for (int off = 1; off < 16; off <<= 1) {
                float ov = __shfl_xor(bv, off);
                int   oi = __shfl_xor(bi, off);
                if (ov < bv || (ov == bv && oi < bi)) { bv = ov; bi = oi; }
            }
            if ((l & 15) == 0) {
                int Rt = mt * MT + wm * QROWS + mi * 16 + (l >> 4) * 4 + rg;
                int rid = sb[Rt];
                if (rid >= 0) {
                    unsigned u = __float_as_uint(bv);
                    unsigned key = (u >> 31) ? ~u : (u | 0x80000000u);
                    atomicMin(&packed[pbase + rid],
                              ((unsigned long long)key << 32) | (unsigned)bi);
                }
            }
        }
    }
}

// ---------------- build CSR lists; iter1 also emits iter2 score list --------
__global__ __launch_bounds__(1024) void k_lists(
    const unsigned long long* __restrict__ packed, int selfSeed,
    unsigned long long* __restrict__ packedOther,
    int2* __restrict__ cb, int* __restrict__ lstIdx, int* __restrict__ ctrOf,
    int* __restrict__ totalPos, int* __restrict__ scoreIdx2)
{
    __shared__ int cntL[NK];
    __shared__ int wsum[16];
    __shared__ int hwsum[16];
    __shared__ int cursor[NK];
    __shared__ int aSh[NM];
    __shared__ int totSh, hitSh;
    int b = blockIdx.x, tid = threadIdx.x;
    cntL[tid] = 0;
    __syncthreads();
    if (selfSeed) {
        if (tid < NN) {
            int a = (int)(unsigned)(packed[(size_t)b * NM + NK + tid] & 0xffffffffull);
            aSh[tid] = a;
            atomicAdd(&cntL[a], 1);
        }
    } else {
        for (int m = tid; m < NM; m += 1024) {
            int a = (int)(unsigned)(packed[(size_t)b * NM + m] & 0xffffffffull);
            aSh[m] = a;
            atomicAdd(&cntL[a], 1);
        }
    }
    for (int m = tid; m < NM; m += 1024)
        packedOther[(size_t)b * NM + m] = ~0ull;
    __syncthreads();
    int v0 = cntL[tid];
    int v = selfSeed ? (v0 ? v0 + 1 : 0) : v0;
    int hit = (selfSeed && v0 > 0) ? 1 : 0;
    int lane = tid & 63, wv = tid >> 6;
    int x = v, hx = hit;
#pragma unroll
    for (int off = 1; off < 64; off <<= 1) {
        int y = __shfl_up(x, off);
        int hy = __shfl_up(hx, off);
        if (lane >= off) { x += y; hx += hy; }
    }
    if (lane == 63) { wsum[wv] = x; hwsum[wv] = hx; }
    __syncthreads();
    if (tid < 16) {
        int s = wsum[tid];
        int e = s;
#pragma unroll
        for (int off = 1; off < 16; off <<= 1) {
            int y = __shfl_up(e, off, 16);
            if (tid >= off) e += y;
        }
        wsum[tid] = e - s;
    } else if (tid < 32) {
        int s = hwsum[tid - 16];
        int e = s;
#pragma unroll
        for (int off = 1; off < 16; off <<= 1) {
            int y = __shfl_up(e, off, 16);
            if ((tid - 16) >= off) e += y;
        }
        hwsum[tid - 16] = e - s;
    }
    __syncthreads();
    int base = x + wsum[wv] - v;               // exclusive prefix of v
    int hb = hx + hwsum[wv] - hit;             // exclusive prefix of hits
    cursor[tid] = base + ((selfSeed && v0) ? 1 : 0);
    cb[b * NK + tid] = make_int2(v, base);
    if (selfSeed && v0) {                      // self entry first (row = tid)
        lstIdx[(size_t)b * NM + base] = tid;
        ctrOf[(size_t)b * NM + base] = tid;
    }
    if (selfSeed) {
        packedOther[(size_t)b * NM + tid] = hit ? ~0ull : (unsigned long long)(unsigned)tid;
        if (tid < NN) packedOther[(size_t)b * NM + NK + tid] = ~0ull;
        if (hit) scoreIdx2[b * 512 + 256 + hb] = tid;
        if (tid < 256) scoreIdx2[b * 512 + tid] = NK + tid;
        if (tid == 1023) hitSh = hb + hit;
    }
    if (tid == 1023) totSh = base + v;
    __syncthreads();
    if (selfSeed) {
        if (tid < NN) {
            int a = aSh[tid];
            int pos = atomicAdd(&cursor[a], 1);
            lstIdx[(size_t)b * NM + pos] = NK + tid;
            ctrOf[(size_t)b * NM + pos] = a;
        }
        int H = hitSh;
        if (tid >= H && tid < 256) scoreIdx2[b * 512 + 256 + tid] = -1;
        if (tid == 0) {
            int total = totSh;
            int padEnd = (total + 7) & ~7;
            for (int p2 = total; p2 < padEnd; ++p2) {
                lstIdx[(size_t)b * NM + p2] = 0;
                ctrOf[(size_t)b * NM + p2] = -1;
            }
            totalPos[b] = total;
        }
    } else {
        for (int m = tid; m < NM; m += 1024) {
            int a = aSh[m];
            int pos = atomicAdd(&cursor[a], 1);
            lstIdx[(size_t)b * NM + pos] = m;
            ctrOf[(size_t)b * NM + pos] = a;
        }
        if (tid == 0) totalPos[b] = NM;
    }
}

// ---------------- stage A: per-8-position segment partial sums --------------
__global__ __launch_bounds__(256) void k_part(
    const float* __restrict__ memF, const float* __restrict__ V, int t,
    const float* __restrict__ cntF,
    const int* __restrict__ lstIdx, const int* __restrict__ ctrOf,
    const int* __restrict__ totalPos,
    float* __restrict__ part, float* __restrict__ partW)
{
    int g = blockIdx.x * 4 + (threadIdx.x >> 6);   // 0..1919
    int l = threadIdx.x & 63;
    int b = g / 480;
    int rem = g - b * 480;
    int seg = rem / 3, c = rem - seg * 3;
    int pos0 = seg * 8;
    if (pos0 >= totalPos[b]) return;
    const int* li = lstIdx + (size_t)b * NM;
    const int* co = ctrOf + (size_t)b * NM;
    int ctr[8]; float wg[8]; float4 xv[8];
#pragma unroll
    for (int i = 0; i < 8; ++i) {
        int p = pos0 + i;
        int cc = co[p];
        int mm = li[p];
        bool pad = cc < 0;
        ctr[i] = pad ? -2 : cc;
        wg[i] = pad ? 0.f : ((mm < NK) ? cntF[b * NK + mm] : 1.0f);
        int mload = pad ? 0 : mm;
        const float4* dr = (mload < NK)
            ? (const float4*)(memF + ((size_t)b * NK + mload) * ND)
            : (const float4*)(V + (((size_t)b * NT + t) * NN + (mload - NK)) * (size_t)ND);
        xv[i] = dr[c * 64 + l];
    }
    float4 acc; float sw; int cur = ctr[0];
    acc.x = wg[0] * xv[0].x; acc.y = wg[0] * xv[0].y;
    acc.z = wg[0] * xv[0].z; acc.w = wg[0] * xv[0].w;
    sw = wg[0];
#pragma unroll
    for (int i = 1; i < 8; ++i) {
        if (ctr[i] != cur) {
            int e = pos0 + i - 1;
            ((float4*)(part + ((size_t)b * NM + e) * ND))[c * 64 + l] = acc;
            if (c == 0 && l == 0) partW[b * NM + e] = sw;
            cur = ctr[i];
            acc.x = wg[i] * xv[i].x; acc.y = wg[i] * xv[i].y;
            acc.z = wg[i] * xv[i].z; acc.w = wg[i] * xv[i].w;
            sw = wg[i];
        } else {
            acc.x += wg[i] * xv[i].x; acc.y += wg[i] * xv[i].y;
            acc.z += wg[i] * xv[i].z; acc.w += wg[i] * xv[i].w;
            sw += wg[i];
        }
    }
    int e = pos0 + 7;
    ((float4*)(part + ((size_t)b * NM + e) * ND))[c * 64 + l] = acc;
    if (c == 0 && l == 0) partW[b * NM + e] = sw;
}

// ---------------- stage B: combine segment partials, write center ----------
// iter1Mode=1: n==0 -> copy fp32 Cen row, count=old count; skip Cout write.
// iter1Mode=0: trivial clusters (n==1, pre-self-assigned row) skip entirely
//              (in-place buffers already hold the correct values);
//              n==0 -> reconstruct center = h+lo from cenHin/cenLin.
__global__ __launch_bounds__(256) void k_upd(
    const float* __restrict__ Cen,
    const f16* __restrict__ cenHin, const f16* __restrict__ cenLin,
    const int2* __restrict__ cb,
    const float* __restrict__ part, const float* __restrict__ partW,
    const float* __restrict__ cntFS,
    const unsigned long long* __restrict__ packedIn, int iter1Mode,
    float* __restrict__ Cout, float* __restrict__ cntOut,
    f16* __restrict__ outH, f16* __restrict__ outL,
    float* __restrict__ cnP)
{
    int g = blockIdx.x * 4 + (threadIdx.x >> 6);   // 0..12287
    int lane = threadIdx.x & 63;
    int row = g / 3, c = g - row * 3;              // row = b*NK+k, chunk c
    int b = row >> 10, k = row & 1023;
    int2 cnb = cb[row];
    int n = cnb.x, base = cnb.y;
    if (!iter1Mode && n == 1 &&
        (packedIn[(size_t)b * NM + k] >> 32) == 0)
        return;                                    // trivial: nothing changes
    float4 vv;
    float sumw = 0.f;
    if (n == 0) {
        if (iter1Mode) {
            vv = ((const float4*)(Cen + (size_t)row * ND))[c * 64 + lane];
            sumw = cntFS[row];
        } else {
            f16x4 hh = ((const f16x4*)(cenHin + (size_t)row * ND))[c * 64 + lane];
            f16x4 ll = ((const f16x4*)(cenLin + (size_t)row * ND))[c * 64 + lane];
            vv.x = (float)hh[0] + (float)ll[0];
            vv.y = (float)hh[1] + (float)ll[1];
            vv.z = (float)hh[2] + (float)ll[2];
            vv.w = (float)hh[3] + (float)ll[3];
            sumw = 0.f;
        }
    } else {
        float4 acc = {0.f, 0.f, 0.f, 0.f};
        int last = base + n - 1;
        int s1 = last >> 3;
        for (int s = base >> 3; s <= s1; ++s) {
            int e = (8 * s + 7 < last) ? (8 * s + 7) : last;
            float4 x = ((const float4*)(part + ((size_t)b * NM + e) * ND))[c * 64 + lane];
            acc.x += x.x; acc.y += x.y; acc.z += x.z; acc.w += x.w;
            sumw += partW[b * NM + e];
        }
        float inv = 1.0f / (sumw + 1e-8f);
        vv.x = acc.x * inv; vv.y = acc.y * inv; vv.z = acc.z * inv; vv.w = acc.w * inv;
    }
    if (!iter1Mode)
        ((float4*)(Cout + (size_t)row * ND))[c * 64 + lane] = vv;
    f16x4 h, lo;
    h[0] = (f16)vv.x; lo[0] = (f16)(vv.x - (float)h[0]);
    h[1] = (f16)vv.y; lo[1] = (f16)(vv.y - (float)h[1]);
    h[2] = (f16)vv.z; lo[2] = (f16)(vv.z - (float)h[2]);
    h[3] = (f16)vv.w; lo[3] = (f16)(vv.w - (float)h[3]);
    ((f16x4*)(outH + (size_t)row * ND))[c * 64 + lane] = h;
    ((f16x4*)(outL + (size_t)row * ND))[c * 64 + lane] = lo;
    float s2 = vv.x * vv.x + vv.y * vv.y + vv.z * vv.z + vv.w * vv.w;
#pragma unroll
    for (int off = 32; off; off >>= 1) s2 += __shfl_xor(s2, off);
    if (lane == 0) cnP[row * 3 + c] = s2;
    if (lane == 0 && c == 0) cntOut[row] = sumw;
}

// ---------------- final: publish memory to d_out ----------------
__global__ __launch_bounds__(256) void k_copy(const float* __restrict__ memF,
                                              float* __restrict__ out) {
    size_t i = (size_t)blockIdx.x * 256 + threadIdx.x;   // 786432 float4
    ((float4*)out)[i] = ((const float4*)memF)[i];
}

// ---------------- host ----------------
extern "C" void kernel_launch(void* const* d_in, const int* in_sizes, int n_in,
                              void* d_out, int out_size, void* d_ws, size_t ws_size,
                              hipStream_t stream) {
    const float* V = (const float*)d_in[0];
    float* out = (float*)d_out;
    char* p = (char*)d_ws;
    auto take = [&](size_t bytes) { char* r = p; p += (bytes + 255) & ~(size_t)255; return r; };

    const size_t fixedBytes = 60ull * 1024 * 1024;
    const size_t fullTokBytes = 2ull * NB * NFRAMES * NN * ND * 2;
    const bool full = ws_size >= fixedBytes + fullTokBytes;
    const size_t tokBS = full ? (size_t)NFRAMES * NN * ND : (size_t)NN * ND;

    float* memF = (float*)take((size_t)NB * NK * ND * 4);
    float* cnt  = (float*)take(NB * NK * 4);
    float* cntS = (float*)take(NB * NK * 4);
    float* cnP  = (float*)take(NB * NK * 3 * 4);
    unsigned long long* packed0 = (unsigned long long*)take(NB * NM * 8);
    unsigned long long* packed1 = (unsigned long long*)take(NB * NM * 8);
    int2* cbBuf  = (int2*)take(NB * NK * 8);
    int*  lstIdx = (int*)take(NB * NM * 4);
    int*  ctrOf  = (int*)take(NB * NM * 4);
    int*  totalPos = (int*)take(NB * 4);
    int*  scoreIdxTok = (int*)take(NB * 512 * 4);
    int*  scoreIdx2   = (int*)take(NB * 512 * 4);
    float* partW = (float*)take(NB * NM * 4);
    float* partB = (float*)take((size_t)NB * NM * ND * 4);
    f16* memH = (f16*)take((size_t)NB * NK * ND * 2);
    f16* memL = (f16*)take((size_t)NB * NK * ND * 2);
    f16* cenH = (f16*)take((size_t)NB * NK * ND * 2);
    f16* cenL = (f16*)take((size_t)NB * NK * ND * 2);
    f16* tokH = (f16*)take((size_t)NB * tokBS * 2);
    f16* tokL = (f16*)take((size_t)NB * tokBS * 2);

    k_init<<<1024, 256, 0, stream>>>(V, memF, cnt, memH, memL, cnP, packed0, scoreIdxTok);
    if (full)
        k_prep<<<NB * NFRAMES * NN / 4, 256, 0, stream>>>(V, NINIT, NFRAMES, tokH, tokL, tokBS);

    for (int f = 0; f < NFRAMES; ++f) {
        int t = NINIT + f;
        const f16* tH = full ? tokH + (size_t)f * NN * ND : tokH;
        const f16* tL = full ? tokL + (size_t)f * NN * ND : tokL;

        if (!full)
            k_prep<<<NB * NN / 4, 256, 0, stream>>>(V, t, 1, tokH, tokL, tokBS);

        // iter 1: score 256 tokens vs memory centers (M=256, 4 mTiles).
        k_scoreX<<<256, 512, 0, stream>>>(scoreIdxTok, 4, memH, memL, tH, tL, tokBS,
                                          memH, memL, cnP, packed0);
        k_lists<<<NB, 1024, 0, stream>>>(packed0, 1, packed1, cbBuf, lstIdx, ctrOf,
                                         totalPos, scoreIdx2);
        k_part<<<480, 256, 0, stream>>>(memF, V, t, cnt, lstIdx, ctrOf, totalPos, partB, partW);
        k_upd<<<3072, 256, 0, stream>>>(memF, cenH, cenL, cbBuf, partB, partW, cnt,
                                        packed1, 1, memF, cntS, cenH, cenL, cnP);

        // iter 2: score only tokens + hit rows (M<=512, 8 mTiles) vs temp centers;
        // unhit memory rows provably self-assign (pre-written in packed1).
        k_scoreX<<<512, 512, 0, stream>>>(scoreIdx2, 8, memH, memL, tH, tL, tokBS,
                                          cenH, cenL, cnP, packed1);
        k_lists<<<NB, 1024, 0, stream>>>(packed1, 0, packed0, cbBuf, lstIdx, ctrOf,
                                         totalPos, scoreIdx2);
        k_part<<<480, 256, 0, stream>>>(memF, V, t, cnt, lstIdx, ctrOf, totalPos, partB, partW);
        k_upd<<<3072, 256, 0, stream>>>(memF, cenH, cenL, cbBuf, partB, partW, cnt,
                                        packed1, 0, memF, cnt, memH, memL, cnP);
    }

    k_copy<<<3072, 256, 0, stream>>>(memF, out);
}

// Round 15
// 2518.513 us; speedup vs baseline: 1.2501x; 1.0141x over previous
//
#include <hip/hip_runtime.h>

#define NB 4
#define NT 32
#define ND 768
#define NK 1024
#define NN 256
#define NINIT 4
#define NFRAMES 28
#define NM 1280

typedef _Float16 f16;
typedef f16 f16x8 __attribute__((ext_vector_type(8)));
typedef f16 f16x4 __attribute__((ext_vector_type(4)));
typedef float f32x4 __attribute__((ext_vector_type(4)));

#define GLOAD_LDS(g, s) __builtin_amdgcn_global_load_lds( \
    (const __attribute__((address_space(1))) void*)(g),   \
    (__attribute__((address_space(3))) void*)(s), 16, 0, 0)

// row-dependent XOR swizzle, closed within a 64-byte row (bits 4-5 only).
__device__ __forceinline__ int swz(int r) { return ((r >> 1) & 3) << 4; }

// ---------------- init: mem copy, counts=1, f16 split, cnorm partials, reset --
__global__ __launch_bounds__(256) void k_init(
    const float* __restrict__ V, float* __restrict__ memF, float* __restrict__ cnt,
    f16* __restrict__ mH, f16* __restrict__ mL,
    float* __restrict__ cnP, unsigned long long* __restrict__ packed0,
    int* __restrict__ scoreIdxTok)
{
    int gid = blockIdx.x * 256 + threadIdx.x;
    if (gid < NB * 512) {                      // constant iter1 score index list
        int i = gid & 511;
        scoreIdxTok[gid] = (i < 256) ? NK + i : -1;
    }
    int row = blockIdx.x * 4 + (threadIdx.x >> 6);   // 0..4095
    int lane = threadIdx.x & 63;
    int b = row >> 10, k = row & 1023;
    const float4* src = (const float4*)(V + ((size_t)b * NT * NN + k) * ND);
    float4* mrow = (float4*)(memF + (size_t)row * ND);
    f16x4* hrow = (f16x4*)(mH + (size_t)row * ND);
    f16x4* lrow = (f16x4*)(mL + (size_t)row * ND);
    float s2 = 0.f;
#pragma unroll
    for (int jj = 0; jj < 3; ++jj) {
        float4 x = src[lane + 64 * jj];
        mrow[lane + 64 * jj] = x;
        f16x4 h, lo;
        h[0] = (f16)x.x; lo[0] = (f16)(x.x - (float)h[0]);
        h[1] = (f16)x.y; lo[1] = (f16)(x.y - (float)h[1]);
        h[2] = (f16)x.z; lo[2] = (f16)(x.z - (float)h[2]);
        h[3] = (f16)x.w; lo[3] = (f16)(x.w - (float)h[3]);
        hrow[lane + 64 * jj] = h;
        lrow[lane + 64 * jj] = lo;
        s2 += x.x * x.x + x.y * x.y + x.z * x.z + x.w * x.w;
    }
#pragma unroll
    for (int off = 32; off; off >>= 1) s2 += __shfl_xor(s2, off);
    if (lane == 0) {
        cnP[row * 3] = s2; cnP[row * 3 + 1] = 0.f; cnP[row * 3 + 2] = 0.f;
        cnt[row] = 1.0f; packed0[(size_t)b * NM + k] = ~0ull;
    }
    if (lane == 1 && k < NN) packed0[(size_t)b * NM + NK + k] = ~0ull;
}

// ---------------- token split: frames t0..t0+nF-1 -> slots 0..nF-1 ----------
__global__ __launch_bounds__(256) void k_prep(
    const float* __restrict__ V, int t0, int nF,
    f16* __restrict__ tokH, f16* __restrict__ tokL, size_t tokBS)
{
    int g = blockIdx.x * 4 + (threadIdx.x >> 6);
    int lane = threadIdx.x & 63;
    int perB = nF * NN;
    if (g >= NB * perB) return;
    int b = g / perB;
    int rem = g - b * perB;
    int fi = rem / NN, n = rem - fi * NN;
    const float4* src = (const float4*)(V + (((size_t)b * NT + t0 + fi) * NN + n) * ND);
    f16x4* hrow = (f16x4*)(tokH + (size_t)b * tokBS + (size_t)(fi * NN + n) * ND);
    f16x4* lrow = (f16x4*)(tokL + (size_t)b * tokBS + (size_t)(fi * NN + n) * ND);
#pragma unroll
    for (int jj = 0; jj < 3; ++jj) {
        float4 x = src[lane + 64 * jj];
        f16x4 h, lo;
        h[0] = (f16)x.x; lo[0] = (f16)(x.x - (float)h[0]);
        h[1] = (f16)x.y; lo[1] = (f16)(x.y - (float)h[1]);
        h[2] = (f16)x.z; lo[2] = (f16)(x.z - (float)h[2]);
        h[3] = (f16)x.w; lo[3] = (f16)(x.w - (float)h[3]);
        hrow[lane + 64 * jj] = h;
        lrow[lane + 64 * jj] = lo;
    }
}

// -------- index-gathered MFMA score: MT=64 split-D 8-wave blocks ------------
// A rows come from sidx[b][0..511] (mem row id <NK, token id >=NK, -1 = pad).
// B centers: hitF ? (hit -> BH/BL, unhit -> MH/ML) : BH/BL.
__global__ __launch_bounds__(512) void k_scoreX(
    const int* __restrict__ sidx, int mTiles,
    const f16* __restrict__ MH, const f16* __restrict__ ML,
    const f16* __restrict__ TH, const f16* __restrict__ TL, size_t tokBS,
    const f16* __restrict__ BH, const f16* __restrict__ BL,
    const int* __restrict__ hitF,
    const float* __restrict__ cnP,
    unsigned long long* __restrict__ packed)
{
    constexpr int MT = 64;
    constexpr int FM = 2;
    constexpr int QROWS = 32;
    constexpr int ASL = 4;
    constexpr int SLOTS = 16;
    constexpr int SPW = 4;
    constexpr int RSZ = SLOTS * 1024;

    __shared__ float4 ldsbuf[SLOTS * 128];   // 32 KB: 2 D-half regions x 16 KB
    char* lds = (char*)ldsbuf;

    int bid = blockIdx.x;
    int cpx = (int)gridDim.x >> 3;
    int sz = (bid & 7) * cpx + (bid >> 3);   // XCD-aware (grid % 8 == 0)
    int pb = mTiles * 16;
    int b = sz / pb;
    int rem = sz - b * pb;
    int mt = rem >> 4, kt = rem & 15;
    const int* sb = sidx + b * 512;
    if (sb[mt * MT] < 0) return;             // fully-padded M tile (monotone pad)
    int tid = threadIdx.x;
    int w = tid >> 6, l = tid & 63;
    int h = w >> 2, q = w & 3;
    int wm = q >> 1, wk = q & 1;
    const int REG = h * RSZ;

    const char* sp[SPW];
#pragma unroll
    for (int i = 0; i < SPW; ++i) {
        int slot = q * SPW + i;
        const f16* base; int r;
        if (slot < ASL) {
            r = slot * 16 + (l >> 2);
            int rid = sb[mt * MT + r]; if (rid < 0) rid = 0;
            base = (rid < NK) ? MH + ((size_t)b * NK + rid) * ND
                              : TH + (size_t)b * tokBS + (size_t)(rid - NK) * ND;
        } else if (slot < 2 * ASL) {
            r = (slot - ASL) * 16 + (l >> 2);
            int rid = sb[mt * MT + r]; if (rid < 0) rid = 0;
            base = (rid < NK) ? ML + ((size_t)b * NK + rid) * ND
                              : TL + (size_t)b * tokBS + (size_t)(rid - NK) * ND;
        } else if (slot < 2 * ASL + 4) {
            r = (slot - 2 * ASL) * 16 + (l >> 2);
            int kc = kt * 64 + r;
            const f16* bb = BH;
            if (hitF && !hitF[b * NK + kc]) bb = MH;
            base = bb + ((size_t)b * NK + kc) * ND;
        } else {
            r = (slot - 2 * ASL - 4) * 16 + (l >> 2);
            int kc = kt * 64 + r;
            const f16* bb = BL;
            if (hitF && !hitF[b * NK + kc]) bb = ML;
            base = bb + ((size_t)b * NK + kc) * ND;
        }
        int colB = ((l & 3) * 16) ^ swz(r);
        sp[i] = (const char*)base + h * 768 + colB;
    }

    int aoffH[FM], aoffL[FM], boffH[2], boffL[2];
#pragma unroll
    for (int mi = 0; mi < FM; ++mi) {
        int r = wm * QROWS + mi * 16 + (l & 15);
        int off = r * 64 + (((l >> 4) * 16) ^ swz(r));
        aoffH[mi] = REG + off;
        aoffL[mi] = REG + ASL * 1024 + off;
    }
#pragma unroll
    for (int nj = 0; nj < 2; ++nj) {
        int rB = wk * 32 + nj * 16 + (l & 15);
        int off = rB * 64 + (((l >> 4) * 16) ^ swz(rB));
        boffH[nj] = REG + 2 * ASL * 1024 + off;
        boffL[nj] = REG + 2 * ASL * 1024 + 4096 + off;
    }

    f32x4 acc[FM][2] = {};

    for (int c = 0; c < 12; ++c) {
#pragma unroll
        for (int i = 0; i < SPW; ++i) {
            GLOAD_LDS(sp[i], lds + REG + (q * SPW + i) * 1024);
            sp[i] += 64;
        }
        __syncthreads();
        f16x8 ah[FM], al[FM], bh[2], bl[2];
#pragma unroll
        for (int mi = 0; mi < FM; ++mi) {
            ah[mi] = *(const f16x8*)(lds + aoffH[mi]);
            al[mi] = *(const f16x8*)(lds + aoffL[mi]);
        }
#pragma unroll
        for (int nj = 0; nj < 2; ++nj) {
            bh[nj] = *(const f16x8*)(lds + boffH[nj]);
            bl[nj] = *(const f16x8*)(lds + boffL[nj]);
        }
#pragma unroll
        for (int mi = 0; mi < FM; ++mi)
#pragma unroll
            for (int nj = 0; nj < 2; ++nj) {
                acc[mi][nj] = __builtin_amdgcn_mfma_f32_16x16x32_f16(ah[mi], bh[nj], acc[mi][nj], 0, 0, 0);
                acc[mi][nj] = __builtin_amdgcn_mfma_f32_16x16x32_f16(ah[mi], bl[nj], acc[mi][nj], 0, 0, 0);
                acc[mi][nj] = __builtin_amdgcn_mfma_f32_16x16x32_f16(al[mi], bh[nj], acc[mi][nj], 0, 0, 0);
            }
        __syncthreads();
    }

    int coff = q * (QROWS * 128) + l * 16;
    if (h == 1) {
#pragma unroll
        for (int mi = 0; mi < FM; ++mi)
#pragma unroll
            for (int nj = 0; nj < 2; ++nj)
                *(f32x4*)(lds + coff + (mi * 2 + nj) * 1024) = acc[mi][nj];
    }
    __syncthreads();
    if (h != 0) return;
#pragma unroll
    for (int mi = 0; mi < FM; ++mi)
#pragma unroll
        for (int nj = 0; nj < 2; ++nj)
            acc[mi][nj] += *(const f32x4*)(lds + coff + (mi * 2 + nj) * 1024);

    int colb = kt * 64 + wk * 32 + (l & 15);
    float cn[2];
#pragma unroll
    for (int nj = 0; nj < 2; ++nj) {
        int kc = b * NK + colb + nj * 16;
        cn[nj] = cnP[kc * 3] + cnP[kc * 3 + 1] + cnP[kc * 3 + 2];
    }
    size_t pbase = (size_t)b * NM;
#pragma unroll
    for (int mi = 0; mi < FM; ++mi) {
#pragma unroll
        for (int rg = 0; rg < 4; ++rg) {
            float bv = 1e30f; int bi = 0;
#pragma unroll
            for (int nj = 0; nj < 2; ++nj) {
                float s = cn[nj] - 2.0f * acc[mi][nj][rg];
                int ki = colb + nj * 16;
                if (s < bv) { bv = s; bi = ki; }
            }
#pragma unroll
            for (int off = 1; off < 16; off <<= 1) {
                float ov = __shfl_xor(bv, off);
                int   oi = __shfl_xor(bi, off);
                if (ov < bv || (ov == bv && oi < bi)) { bv = ov; bi = oi; }
            }
            if ((l & 15) == 0) {
                int Rt = mt * MT + wm * QROWS + mi * 16 + (l >> 4) * 4 + rg;
                int rid = sb[Rt];
                if (rid >= 0) {
                    unsigned u = __float_as_uint(bv);
                    unsigned key = (u >> 31) ? ~u : (u | 0x80000000u);
                    atomicMin(&packed[pbase + rid],
                              ((unsigned long long)key << 32) | (unsigned)bi);
                }
            }
        }
    }
}

// ---------------- build CSR lists; iter1 also emits iter2 score list + hitF --
__global__ __launch_bounds__(1024) void k_lists(
    const unsigned long long* __restrict__ packed, int selfSeed,
    unsigned long long* __restrict__ packedOther,
    int2* __restrict__ cb, int* __restrict__ lstIdx, int* __restrict__ ctrOf,
    int* __restrict__ totalPos, int* __restrict__ scoreIdx2,
    int* __restrict__ hitF)
{
    __shared__ int cntL[NK];
    __shared__ int wsum[16];
    __shared__ int hwsum[16];
    __shared__ int cursor[NK];
    __shared__ int aSh[NM];
    __shared__ int totSh, hitSh;
    int b = blockIdx.x, tid = threadIdx.x;
    cntL[tid] = 0;
    __syncthreads();
    if (selfSeed) {
        if (tid < NN) {
            int a = (int)(unsigned)(packed[(size_t)b * NM + NK + tid] & 0xffffffffull);
            aSh[tid] = a;
            atomicAdd(&cntL[a], 1);
        }
    } else {
        for (int m = tid; m < NM; m += 1024) {
            int a = (int)(unsigned)(packed[(size_t)b * NM + m] & 0xffffffffull);
            aSh[m] = a;
            atomicAdd(&cntL[a], 1);
        }
    }
    for (int m = tid; m < NM; m += 1024)
        packedOther[(size_t)b * NM + m] = ~0ull;
    __syncthreads();
    int v0 = cntL[tid];
    int v = selfSeed ? (v0 ? v0 + 1 : 0) : v0;
    int hit = (selfSeed && v0 > 0) ? 1 : 0;
    int lane = tid & 63, wv = tid >> 6;
    int x = v, hx = hit;
#pragma unroll
    for (int off = 1; off < 64; off <<= 1) {
        int y = __shfl_up(x, off);
        int hy = __shfl_up(hx, off);
        if (lane >= off) { x += y; hx += hy; }
    }
    if (lane == 63) { wsum[wv] = x; hwsum[wv] = hx; }
    __syncthreads();
    if (tid < 16) {
        int s = wsum[tid];
        int e = s;
#pragma unroll
        for (int off = 1; off < 16; off <<= 1) {
            int y = __shfl_up(e, off, 16);
            if (tid >= off) e += y;
        }
        wsum[tid] = e - s;
    } else if (tid < 32) {
        int s = hwsum[tid - 16];
        int e = s;
#pragma unroll
        for (int off = 1; off < 16; off <<= 1) {
            int y = __shfl_up(e, off, 16);
            if ((tid - 16) >= off) e += y;
        }
        hwsum[tid - 16] = e - s;
    }
    __syncthreads();
    int base = x + wsum[wv] - v;               // exclusive prefix of v
    int hb = hx + hwsum[wv] - hit;             // exclusive prefix of hits
    cursor[tid] = base + ((selfSeed && v0) ? 1 : 0);
    cb[b * NK + tid] = make_int2(v, base);
    if (selfSeed && v0) {                      // self entry first (row = tid)
        lstIdx[(size_t)b * NM + base] = tid;
        ctrOf[(size_t)b * NM + base] = tid;
    }
    if (selfSeed) {
        hitF[b * NK + tid] = hit;
        packedOther[(size_t)b * NM + tid] = hit ? ~0ull : (unsigned long long)(unsigned)tid;
        if (tid < NN) packedOther[(size_t)b * NM + NK + tid] = ~0ull;
        if (hit) scoreIdx2[b * 512 + 256 + hb] = tid;
        if (tid < 256) scoreIdx2[b * 512 + tid] = NK + tid;
        if (tid == 1023) hitSh = hb + hit;
    }
    if (tid == 1023) totSh = base + v;
    __syncthreads();
    if (selfSeed) {
        if (tid < NN) {
            int a = aSh[tid];
            int pos = atomicAdd(&cursor[a], 1);
            lstIdx[(size_t)b * NM + pos] = NK + tid;
            ctrOf[(size_t)b * NM + pos] = a;
        }
        int H = hitSh;
        if (tid >= H && tid < 256) scoreIdx2[b * 512 + 256 + tid] = -1;
        if (tid == 0) {
            int total = totSh;
            int padEnd = (total + 7) & ~7;
            for (int p2 = total; p2 < padEnd; ++p2) {
                lstIdx[(size_t)b * NM + p2] = 0;
                ctrOf[(size_t)b * NM + p2] = -1;
            }
            totalPos[b] = total;
        }
    } else {
        for (int m = tid; m < NM; m += 1024) {
            int a = aSh[m];
            int pos = atomicAdd(&cursor[a], 1);
            lstIdx[(size_t)b * NM + pos] = m;
            ctrOf[(size_t)b * NM + pos] = a;
        }
        if (tid == 0) totalPos[b] = NM;
    }
}

// ---------------- stage A: per-8-position segment partial sums --------------
__global__ __launch_bounds__(256) void k_part(
    const float* __restrict__ memF, const float* __restrict__ V, int t,
    const float* __restrict__ cntF,
    const int* __restrict__ lstIdx, const int* __restrict__ ctrOf,
    const int* __restrict__ totalPos,
    float* __restrict__ part, float* __restrict__ partW)
{
    int g = blockIdx.x * 4 + (threadIdx.x >> 6);   // 0..1919
    int l = threadIdx.x & 63;
    int b = g / 480;
    int rem = g - b * 480;
    int seg = rem / 3, c = rem - seg * 3;
    int pos0 = seg * 8;
    if (pos0 >= totalPos[b]) return;
    const int* li = lstIdx + (size_t)b * NM;
    const int* co = ctrOf + (size_t)b * NM;
    int ctr[8]; float wg[8]; float4 xv[8];
#pragma unroll
    for (int i = 0; i < 8; ++i) {
        int p = pos0 + i;
        int cc = co[p];
        int mm = li[p];
        bool pad = cc < 0;
        ctr[i] = pad ? -2 : cc;
        wg[i] = pad ? 0.f : ((mm < NK) ? cntF[b * NK + mm] : 1.0f);
        int mload = pad ? 0 : mm;
        const float4* dr = (mload < NK)
            ? (const float4*)(memF + ((size_t)b * NK + mload) * ND)
            : (const float4*)(V + (((size_t)b * NT + t) * NN + (mload - NK)) * (size_t)ND);
        xv[i] = dr[c * 64 + l];
    }
    float4 acc; float sw; int cur = ctr[0];
    acc.x = wg[0] * xv[0].x; acc.y = wg[0] * xv[0].y;
    acc.z = wg[0] * xv[0].z; acc.w = wg[0] * xv[0].w;
    sw = wg[0];
#pragma unroll
    for (int i = 1; i < 8; ++i) {
        if (ctr[i] != cur) {
            int e = pos0 + i - 1;
            ((float4*)(part + ((size_t)b * NM + e) * ND))[c * 64 + l] = acc;
            if (c == 0 && l == 0) partW[b * NM + e] = sw;
            cur = ctr[i];
            acc.x = wg[i] * xv[i].x; acc.y = wg[i] * xv[i].y;
            acc.z = wg[i] * xv[i].z; acc.w = wg[i] * xv[i].w;
            sw = wg[i];
        } else {
            acc.x += wg[i] * xv[i].x; acc.y += wg[i] * xv[i].y;
            acc.z += wg[i] * xv[i].z; acc.w += wg[i] * xv[i].w;
            sw += wg[i];
        }
    }
    int e = pos0 + 7;
    ((float4*)(part + ((size_t)b * NM + e) * ND))[c * 64 + l] = acc;
    if (c == 0 && l == 0) partW[b * NM + e] = sw;
}

// ---------------- stage B: combine segment partials, write center ----------
// iter1Mode=1: n==0 -> skip entirely (unhit: memH/L + cnP already correct).
// iter1Mode=0: trivial clusters (n==1, pre-self-assigned row) skip entirely;
//              n==0 -> reconstruct center = h+lo from cenHin/cenLin (hit rows only).
__global__ __launch_bounds__(256) void k_upd(
    const f16* __restrict__ cenHin, const f16* __restrict__ cenLin,
    const int2* __restrict__ cb,
    const float* __restrict__ part, const float* __restrict__ partW,
    const unsigned long long* __restrict__ packedIn, int iter1Mode,
    float* __restrict__ Cout, float* __restrict__ cntOut,
    f16* __restrict__ outH, f16* __restrict__ outL,
    float* __restrict__ cnP)
{
    int g = blockIdx.x * 4 + (threadIdx.x >> 6);   // 0..12287
    int lane = threadIdx.x & 63;
    int row = g / 3, c = g - row * 3;              // row = b*NK+k, chunk c
    int b = row >> 10, k = row & 1023;
    int2 cnb = cb[row];
    int n = cnb.x, base = cnb.y;
    if (iter1Mode && n == 0) return;               // unhit: nothing changes
    if (!iter1Mode && n == 1 &&
        (packedIn[(size_t)b * NM + k] >> 32) == 0)
        return;                                    // trivial: nothing changes
    float4 vv;
    float sumw = 0.f;
    if (n == 0) {
        f16x4 hh = ((const f16x4*)(cenHin + (size_t)row * ND))[c * 64 + lane];
        f16x4 ll = ((const f16x4*)(cenLin + (size_t)row * ND))[c * 64 + lane];
        vv.x = (float)hh[0] + (float)ll[0];
        vv.y = (float)hh[1] + (float)ll[1];
        vv.z = (float)hh[2] + (float)ll[2];
        vv.w = (float)hh[3] + (float)ll[3];
        sumw = 0.f;
    } else {
        float4 acc = {0.f, 0.f, 0.f, 0.f};
        int last = base + n - 1;
        int s1 = last >> 3;
        for (int s = base >> 3; s <= s1; ++s) {
            int e = (8 * s + 7 < last) ? (8 * s + 7) : last;
            float4 x = ((const float4*)(part + ((size_t)b * NM + e) * ND))[c * 64 + lane];
            acc.x += x.x; acc.y += x.y; acc.z += x.z; acc.w += x.w;
            sumw += partW[b * NM + e];
        }
        float inv = 1.0f / (sumw + 1e-8f);
        vv.x = acc.x * inv; vv.y = acc.y * inv; vv.z = acc.z * inv; vv.w = acc.w * inv;
    }
    if (!iter1Mode)
        ((float4*)(Cout + (size_t)row * ND))[c * 64 + lane] = vv;
    f16x4 h, lo;
    h[0] = (f16)vv.x; lo[0] = (f16)(vv.x - (float)h[0]);
    h[1] = (f16)vv.y; lo[1] = (f16)(vv.y - (float)h[1]);
    h[2] = (f16)vv.z; lo[2] = (f16)(vv.z - (float)h[2]);
    h[3] = (f16)vv.w; lo[3] = (f16)(vv.w - (float)h[3]);
    ((f16x4*)(outH + (size_t)row * ND))[c * 64 + lane] = h;
    ((f16x4*)(outL + (size_t)row * ND))[c * 64 + lane] = lo;
    float s2 = vv.x * vv.x + vv.y * vv.y + vv.z * vv.z + vv.w * vv.w;
#pragma unroll
    for (int off = 32; off; off >>= 1) s2 += __shfl_xor(s2, off);
    if (lane == 0) cnP[row * 3 + c] = s2;
    if (lane == 0 && c == 0) cntOut[row] = sumw;
}

// ---------------- final: publish memory to d_out ----------------
__global__ __launch_bounds__(256) void k_copy(const float* __restrict__ memF,
                                              float* __restrict__ out) {
    size_t i = (size_t)blockIdx.x * 256 + threadIdx.x;   // 786432 float4
    ((float4*)out)[i] = ((const float4*)memF)[i];
}

// ---------------- host ----------------
extern "C" void kernel_launch(void* const* d_in, const int* in_sizes, int n_in,
                              void* d_out, int out_size, void* d_ws, size_t ws_size,
                              hipStream_t stream) {
    const float* V = (const float*)d_in[0];
    float* out = (float*)d_out;
    char* p = (char*)d_ws;
    auto take = [&](size_t bytes) { char* r = p; p += (bytes + 255) & ~(size_t)255; return r; };

    const size_t fixedBytes = 60ull * 1024 * 1024;
    const size_t fullTokBytes = 2ull * NB * NFRAMES * NN * ND * 2;
    const bool full = ws_size >= fixedBytes + fullTokBytes;
    const size_t tokBS = full ? (size_t)NFRAMES * NN * ND : (size_t)NN * ND;

    float* memF = (float*)take((size_t)NB * NK * ND * 4);
    float* cnt  = (float*)take(NB * NK * 4);
    float* cntS = (float*)take(NB * NK * 4);
    float* cnP  = (float*)take(NB * NK * 3 * 4);
    unsigned long long* packed0 = (unsigned long long*)take(NB * NM * 8);
    unsigned long long* packed1 = (unsigned long long*)take(NB * NM * 8);
    int2* cbBuf  = (int2*)take(NB * NK * 8);
    int*  lstIdx = (int*)take(NB * NM * 4);
    int*  ctrOf  = (int*)take(NB * NM * 4);
    int*  totalPos = (int*)take(NB * 4);
    int*  scoreIdxTok = (int*)take(NB * 512 * 4);
    int*  scoreIdx2   = (int*)take(NB * 512 * 4);
    int*  hitF   = (int*)take(NB * NK * 4);
    float* partW = (float*)take(NB * NM * 4);
    float* partB = (float*)take((size_t)NB * NM * ND * 4);
    f16* memH = (f16*)take((size_t)NB * NK * ND * 2);
    f16* memL = (f16*)take((size_t)NB * NK * ND * 2);
    f16* cenH = (f16*)take((size_t)NB * NK * ND * 2);
    f16* cenL = (f16*)take((size_t)NB * NK * ND * 2);
    f16* tokH = (f16*)take((size_t)NB * tokBS * 2);
    f16* tokL = (f16*)take((size_t)NB * tokBS * 2);

    k_init<<<1024, 256, 0, stream>>>(V, memF, cnt, memH, memL, cnP, packed0, scoreIdxTok);
    if (full)
        k_prep<<<NB * NFRAMES * NN / 4, 256, 0, stream>>>(V, NINIT, NFRAMES, tokH, tokL, tokBS);

    for (int f = 0; f < NFRAMES; ++f) {
        int t = NINIT + f;
        const f16* tH = full ? tokH + (size_t)f * NN * ND : tokH;
        const f16* tL = full ? tokL + (size_t)f * NN * ND : tokL;

        if (!full)
            k_prep<<<NB * NN / 4, 256, 0, stream>>>(V, t, 1, tokH, tokL, tokBS);

        // iter 1: score 256 tokens vs memory centers (M=256, 4 mTiles).
        k_scoreX<<<256, 512, 0, stream>>>(scoreIdxTok, 4, memH, memL, tH, tL, tokBS,
                                          memH, memL, nullptr, cnP, packed0);
        k_lists<<<NB, 1024, 0, stream>>>(packed0, 1, packed1, cbBuf, lstIdx, ctrOf,
                                         totalPos, scoreIdx2, hitF);
        k_part<<<480, 256, 0, stream>>>(memF, V, t, cnt, lstIdx, ctrOf, totalPos, partB, partW);
        k_upd<<<3072, 256, 0, stream>>>(cenH, cenL, cbBuf, partB, partW,
                                        packed1, 1, memF, cntS, cenH, cenL, cnP);

        // iter 2: score tokens + hit rows (M<=512) vs temp centers (hitF-selected);
        // unhit memory rows provably self-assign (pre-written in packed1).
        k_scoreX<<<512, 512, 0, stream>>>(scoreIdx2, 8, memH, memL, tH, tL, tokBS,
                                          cenH, cenL, hitF, cnP, packed1);
        k_lists<<<NB, 1024, 0, stream>>>(packed1, 0, packed0, cbBuf, lstIdx, ctrOf,
                                         totalPos, scoreIdx2, hitF);
        k_part<<<480, 256, 0, stream>>>(memF, V, t, cnt, lstIdx, ctrOf, totalPos, partB, partW);
        k_upd<<<3072, 256, 0, stream>>>(cenH, cenL, cbBuf, partB, partW,
                                        packed1, 0, memF, cnt, memH, memL, cnP);
    }

    k_copy<<<3072, 256, 0, stream>>>(memF, out);
}

// Round 16
// 2370.782 us; speedup vs baseline: 1.3280x; 1.0623x over previous
//
#include <hip/hip_runtime.h>

#define NB 4
#define NT 32
#define ND 768
#define NK 1024
#define NN 256
#define NINIT 4
#define NFRAMES 28
#define NM 1280

typedef _Float16 f16;
typedef f16 f16x8 __attribute__((ext_vector_type(8)));
typedef f16 f16x4 __attribute__((ext_vector_type(4)));
typedef float f32x4 __attribute__((ext_vector_type(4)));

#define GLOAD_LDS(g, s) __builtin_amdgcn_global_load_lds( \
    (const __attribute__((address_space(1))) void*)(g),   \
    (__attribute__((address_space(3))) void*)(s), 16, 0, 0)

// row-dependent XOR swizzle, closed within a 64-byte row (bits 4-5 only).
__device__ __forceinline__ int swz(int r) { return ((r >> 1) & 3) << 4; }

// ---------------- init: mem copy, counts=1, f16 split, cnorm partials, reset --
__global__ __launch_bounds__(256) void k_init(
    const float* __restrict__ V, float* __restrict__ memF, float* __restrict__ cnt,
    f16* __restrict__ mH, f16* __restrict__ mL,
    float* __restrict__ cnP, unsigned long long* __restrict__ packed0,
    int* __restrict__ scoreIdxTok)
{
    int gid = blockIdx.x * 256 + threadIdx.x;
    if (gid < NB * 512) {                      // constant iter1 score index list
        int i = gid & 511;
        scoreIdxTok[gid] = (i < 256) ? NK + i : -1;
    }
    int row = blockIdx.x * 4 + (threadIdx.x >> 6);   // 0..4095
    int lane = threadIdx.x & 63;
    int b = row >> 10, k = row & 1023;
    const float4* src = (const float4*)(V + ((size_t)b * NT * NN + k) * ND);
    float4* mrow = (float4*)(memF + (size_t)row * ND);
    f16x4* hrow = (f16x4*)(mH + (size_t)row * ND);
    f16x4* lrow = (f16x4*)(mL + (size_t)row * ND);
    float s2 = 0.f;
#pragma unroll
    for (int jj = 0; jj < 3; ++jj) {
        float4 x = src[lane + 64 * jj];
        mrow[lane + 64 * jj] = x;
        f16x4 h, lo;
        h[0] = (f16)x.x; lo[0] = (f16)(x.x - (float)h[0]);
        h[1] = (f16)x.y; lo[1] = (f16)(x.y - (float)h[1]);
        h[2] = (f16)x.z; lo[2] = (f16)(x.z - (float)h[2]);
        h[3] = (f16)x.w; lo[3] = (f16)(x.w - (float)h[3]);
        hrow[lane + 64 * jj] = h;
        lrow[lane + 64 * jj] = lo;
        s2 += x.x * x.x + x.y * x.y + x.z * x.z + x.w * x.w;
    }
#pragma unroll
    for (int off = 32; off; off >>= 1) s2 += __shfl_xor(s2, off);
    if (lane == 0) {
        cnP[row * 3] = s2; cnP[row * 3 + 1] = 0.f; cnP[row * 3 + 2] = 0.f;
        cnt[row] = 1.0f; packed0[(size_t)b * NM + k] = ~0ull;
    }
    if (lane == 1 && k < NN) packed0[(size_t)b * NM + NK + k] = ~0ull;
}

// ---------------- token split: frames t0..t0+nF-1 -> slots 0..nF-1 ----------
__global__ __launch_bounds__(256) void k_prep(
    const float* __restrict__ V, int t0, int nF,
    f16* __restrict__ tokH, f16* __restrict__ tokL, size_t tokBS)
{
    int g = blockIdx.x * 4 + (threadIdx.x >> 6);
    int lane = threadIdx.x & 63;
    int perB = nF * NN;
    if (g >= NB * perB) return;
    int b = g / perB;
    int rem = g - b * perB;
    int fi = rem / NN, n = rem - fi * NN;
    const float4* src = (const float4*)(V + (((size_t)b * NT + t0 + fi) * NN + n) * ND);
    f16x4* hrow = (f16x4*)(tokH + (size_t)b * tokBS + (size_t)(fi * NN + n) * ND);
    f16x4* lrow = (f16x4*)(tokL + (size_t)b * tokBS + (size_t)(fi * NN + n) * ND);
#pragma unroll
    for (int jj = 0; jj < 3; ++jj) {
        float4 x = src[lane + 64 * jj];
        f16x4 h, lo;
        h[0] = (f16)x.x; lo[0] = (f16)(x.x - (float)h[0]);
        h[1] = (f16)x.y; lo[1] = (f16)(x.y - (float)h[1]);
        h[2] = (f16)x.z; lo[2] = (f16)(x.z - (float)h[2]);
        h[3] = (f16)x.w; lo[3] = (f16)(x.w - (float)h[3]);
        hrow[lane + 64 * jj] = h;
        lrow[lane + 64 * jj] = lo;
    }
}

// -------- index-gathered MFMA score: MT=64 split-D 8-wave blocks ------------
// Double-buffered LDS + counted vmcnt (R8-validated STAGE pattern).
// A rows come from sidx[b][0..511] (mem row id <NK, token id >=NK, -1 = pad).
// B centers: hitF ? (hit -> BH/BL, unhit -> MH/ML) : BH/BL.
__global__ __launch_bounds__(512) void k_scoreX(
    const int* __restrict__ sidx, int mTiles,
    const f16* __restrict__ MH, const f16* __restrict__ ML,
    const f16* __restrict__ TH, const f16* __restrict__ TL, size_t tokBS,
    const f16* __restrict__ BH, const f16* __restrict__ BL,
    const int* __restrict__ hitF,
    const float* __restrict__ cnP,
    unsigned long long* __restrict__ packed)
{
    constexpr int MT = 64;
    constexpr int FM = 2;
    constexpr int QROWS = 32;
    constexpr int ASL = 4;
    constexpr int SLOTS = 16;
    constexpr int SPW = 4;
    constexpr int RSZ = SLOTS * 1024;        // 16 KB per D-half region

    __shared__ float4 ldsbuf[2 * SLOTS * 128];   // 64 KB: 2 chunk-buffers x 32 KB
    char* lds = (char*)ldsbuf;

    int bid = blockIdx.x;
    int cpx = (int)gridDim.x >> 3;
    int sz = (bid & 7) * cpx + (bid >> 3);   // XCD-aware (grid % 8 == 0)
    int pb = mTiles * 16;
    int b = sz / pb;
    int rem = sz - b * pb;
    int mt = rem >> 4, kt = rem & 15;
    const int* sb = sidx + b * 512;
    if (sb[mt * MT] < 0) return;             // fully-padded M tile (monotone pad)
    int tid = threadIdx.x;
    int w = tid >> 6, l = tid & 63;
    int h = w >> 2, q = w & 3;
    int wm = q >> 1, wk = q & 1;
    const int REG = h * RSZ;

    const char* sp[SPW];
#pragma unroll
    for (int i = 0; i < SPW; ++i) {
        int slot = q * SPW + i;
        const f16* base; int r;
        if (slot < ASL) {
            r = slot * 16 + (l >> 2);
            int rid = sb[mt * MT + r]; if (rid < 0) rid = 0;
            base = (rid < NK) ? MH + ((size_t)b * NK + rid) * ND
                              : TH + (size_t)b * tokBS + (size_t)(rid - NK) * ND;
        } else if (slot < 2 * ASL) {
            r = (slot - ASL) * 16 + (l >> 2);
            int rid = sb[mt * MT + r]; if (rid < 0) rid = 0;
            base = (rid < NK) ? ML + ((size_t)b * NK + rid) * ND
                              : TL + (size_t)b * tokBS + (size_t)(rid - NK) * ND;
        } else if (slot < 2 * ASL + 4) {
            r = (slot - 2 * ASL) * 16 + (l >> 2);
            int kc = kt * 64 + r;
            const f16* bb = BH;
            if (hitF && !hitF[b * NK + kc]) bb = MH;
            base = bb + ((size_t)b * NK + kc) * ND;
        } else {
            r = (slot - 2 * ASL - 4) * 16 + (l >> 2);
            int kc = kt * 64 + r;
            const f16* bb = BL;
            if (hitF && !hitF[b * NK + kc]) bb = ML;
            base = bb + ((size_t)b * NK + kc) * ND;
        }
        int colB = ((l & 3) * 16) ^ swz(r);
        sp[i] = (const char*)base + h * 768 + colB;
    }

    int aoffH[FM], aoffL[FM], boffH[2], boffL[2];
#pragma unroll
    for (int mi = 0; mi < FM; ++mi) {
        int r = wm * QROWS + mi * 16 + (l & 15);
        int off = r * 64 + (((l >> 4) * 16) ^ swz(r));
        aoffH[mi] = REG + off;
        aoffL[mi] = REG + ASL * 1024 + off;
    }
#pragma unroll
    for (int nj = 0; nj < 2; ++nj) {
        int rB = wk * 32 + nj * 16 + (l & 15);
        int off = rB * 64 + (((l >> 4) * 16) ^ swz(rB));
        boffH[nj] = REG + 2 * ASL * 1024 + off;
        boffL[nj] = REG + 2 * ASL * 1024 + 4096 + off;
    }

    f32x4 acc[FM][2] = {};

#define STAGEX(bufbase)                                                   \
    _Pragma("unroll")                                                     \
    for (int i = 0; i < SPW; ++i) {                                       \
        GLOAD_LDS(sp[i], lds + (bufbase) + REG + (q * SPW + i) * 1024);   \
        sp[i] += 64;                                                      \
    }

    STAGEX(0);                                   // prologue: chunk 0 -> buf0
    for (int c = 0; c < 12; ++c) {
        int cur = (c & 1) << 15;                 // 0 or 32768
        if (c < 11) {
            STAGEX(cur ^ 32768);                 // chunk c+1 -> other buffer
            asm volatile("s_waitcnt vmcnt(4)" ::: "memory");   // chunk c landed
        } else {
            asm volatile("s_waitcnt vmcnt(0)" ::: "memory");
        }
        __builtin_amdgcn_s_barrier();
        __builtin_amdgcn_sched_barrier(0);
        f16x8 ah[FM], al[FM], bh[2], bl[2];
#pragma unroll
        for (int mi = 0; mi < FM; ++mi) {
            ah[mi] = *(const f16x8*)(lds + cur + aoffH[mi]);
            al[mi] = *(const f16x8*)(lds + cur + aoffL[mi]);
        }
#pragma unroll
        for (int nj = 0; nj < 2; ++nj) {
            bh[nj] = *(const f16x8*)(lds + cur + boffH[nj]);
            bl[nj] = *(const f16x8*)(lds + cur + boffL[nj]);
        }
#pragma unroll
        for (int mi = 0; mi < FM; ++mi)
#pragma unroll
            for (int nj = 0; nj < 2; ++nj) {
                acc[mi][nj] = __builtin_amdgcn_mfma_f32_16x16x32_f16(ah[mi], bh[nj], acc[mi][nj], 0, 0, 0);
                acc[mi][nj] = __builtin_amdgcn_mfma_f32_16x16x32_f16(ah[mi], bl[nj], acc[mi][nj], 0, 0, 0);
                acc[mi][nj] = __builtin_amdgcn_mfma_f32_16x16x32_f16(al[mi], bh[nj], acc[mi][nj], 0, 0, 0);
            }
        __builtin_amdgcn_sched_barrier(0);
        __builtin_amdgcn_s_barrier();
    }
    __syncthreads();                             // all reads done; reuse buffer 0

    int coff = q * (QROWS * 128) + l * 16;
    if (h == 1) {
#pragma unroll
        for (int mi = 0; mi < FM; ++mi)
#pragma unroll
            for (int nj = 0; nj < 2; ++nj)
                *(f32x4*)(lds + coff + (mi * 2 + nj) * 1024) = acc[mi][nj];
    }
    __syncthreads();
    if (h != 0) return;
#pragma unroll
    for (int mi = 0; mi < FM; ++mi)
#pragma unroll
        for (int nj = 0; nj < 2; ++nj)
            acc[mi][nj] += *(const f32x4*)(lds + coff + (mi * 2 + nj) * 1024);

    int colb = kt * 64 + wk * 32 + (l & 15);
    float cn[2];
#pragma unroll
    for (int nj = 0; nj < 2; ++nj) {
        int kc = b * NK + colb + nj * 16;
        cn[nj] = cnP[kc * 3] + cnP[kc * 3 + 1] + cnP[kc * 3 + 2];
    }
    size_t pbase = (size_t)b * NM;
#pragma unroll
    for (int mi = 0; mi < FM; ++mi) {
#pragma unroll
        for (int rg = 0; rg < 4; ++rg) {
            float bv = 1e30f; int bi = 0;
#pragma unroll
            for (int nj = 0; nj < 2; ++nj) {
                float s = cn[nj] - 2.0f * acc[mi][nj][rg];
                int ki = colb + nj * 16;
                if (s < bv) { bv = s; bi = ki; }
            }
#pragma unroll
            for (int off = 1; off < 16; off <<= 1) {
                float ov = __shfl_xor(bv, off);
                int   oi = __shfl_xor(bi, off);
                if (ov < bv || (ov == bv && oi < bi)) { bv = ov; bi = oi; }
            }
            if ((l & 15) == 0) {
                int Rt = mt * MT + wm * QROWS + mi * 16 + (l >> 4) * 4 + rg;
                int rid = sb[Rt];
                if (rid >= 0) {
                    unsigned u = __float_as_uint(bv);
                    unsigned key = (u >> 31) ? ~u : (u | 0x80000000u);
                    atomicMin(&packed[pbase + rid],
                              ((unsigned long long)key << 32) | (unsigned)bi);
                }
            }
        }
    }
}

// ---------------- build CSR lists; iter1 also emits iter2 score list + hitF --
__global__ __launch_bounds__(1024) void k_lists(
    const unsigned long long* __restrict__ packed, int selfSeed,
    unsigned long long* __restrict__ packedOther,
    int2* __restrict__ cb, int* __restrict__ lstIdx, int* __restrict__ ctrOf,
    int* __restrict__ totalPos, int* __restrict__ scoreIdx2,
    int* __restrict__ hitF)
{
    __shared__ int cntL[NK];
    __shared__ int wsum[16];
    __shared__ int hwsum[16];
    __shared__ int cursor[NK];
    __shared__ int aSh[NM];
    __shared__ int totSh, hitSh;
    int b = blockIdx.x, tid = threadIdx.x;
    cntL[tid] = 0;
    __syncthreads();
    if (selfSeed) {
        if (tid < NN) {
            int a = (int)(unsigned)(packed[(size_t)b * NM + NK + tid] & 0xffffffffull);
            aSh[tid] = a;
            atomicAdd(&cntL[a], 1);
        }
    } else {
        for (int m = tid; m < NM; m += 1024) {
            int a = (int)(unsigned)(packed[(size_t)b * NM + m] & 0xffffffffull);
            aSh[m] = a;
            atomicAdd(&cntL[a], 1);
        }
    }
    for (int m = tid; m < NM; m += 1024)
        packedOther[(size_t)b * NM + m] = ~0ull;
    __syncthreads();
    int v0 = cntL[tid];
    int v = selfSeed ? (v0 ? v0 + 1 : 0) : v0;
    int hit = (selfSeed && v0 > 0) ? 1 : 0;
    int lane = tid & 63, wv = tid >> 6;
    int x = v, hx = hit;
#pragma unroll
    for (int off = 1; off < 64; off <<= 1) {
        int y = __shfl_up(x, off);
        int hy = __shfl_up(hx, off);
        if (lane >= off) { x += y; hx += hy; }
    }
    if (lane == 63) { wsum[wv] = x; hwsum[wv] = hx; }
    __syncthreads();
    if (tid < 16) {
        int s = wsum[tid];
        int e = s;
#pragma unroll
        for (int off = 1; off < 16; off <<= 1) {
            int y = __shfl_up(e, off, 16);
            if (tid >= off) e += y;
        }
        wsum[tid] = e - s;
    } else if (tid < 32) {
        int s = hwsum[tid - 16];
        int e = s;
#pragma unroll
        for (int off = 1; off < 16; off <<= 1) {
            int y = __shfl_up(e, off, 16);
            if ((tid - 16) >= off) e += y;
        }
        hwsum[tid - 16] = e - s;
    }
    __syncthreads();
    int base = x + wsum[wv] - v;               // exclusive prefix of v
    int hb = hx + hwsum[wv] - hit;             // exclusive prefix of hits
    cursor[tid] = base + ((selfSeed && v0) ? 1 : 0);
    cb[b * NK + tid] = make_int2(v, base);
    if (selfSeed && v0) {                      // self entry first (row = tid)
        lstIdx[(size_t)b * NM + base] = tid;
        ctrOf[(size_t)b * NM + base] = tid;
    }
    if (selfSeed) {
        hitF[b * NK + tid] = hit;
        packedOther[(size_t)b * NM + tid] = hit ? ~0ull : (unsigned long long)(unsigned)tid;
        if (tid < NN) packedOther[(size_t)b * NM + NK + tid] = ~0ull;
        if (hit) scoreIdx2[b * 512 + 256 + hb] = tid;
        if (tid < 256) scoreIdx2[b * 512 + tid] = NK + tid;
        if (tid == 1023) hitSh = hb + hit;
    }
    if (tid == 1023) totSh = base + v;
    __syncthreads();
    if (selfSeed) {
        if (tid < NN) {
            int a = aSh[tid];
            int pos = atomicAdd(&cursor[a], 1);
            lstIdx[(size_t)b * NM + pos] = NK + tid;
            ctrOf[(size_t)b * NM + pos] = a;
        }
        int H = hitSh;
        if (tid >= H && tid < 256) scoreIdx2[b * 512 + 256 + tid] = -1;
        if (tid == 0) {
            int total = totSh;
            int padEnd = (total + 7) & ~7;
            for (int p2 = total; p2 < padEnd; ++p2) {
                lstIdx[(size_t)b * NM + p2] = 0;
                ctrOf[(size_t)b * NM + p2] = -1;
            }
            totalPos[b] = total;
        }
    } else {
        for (int m = tid; m < NM; m += 1024) {
            int a = aSh[m];
            int pos = atomicAdd(&cursor[a], 1);
            lstIdx[(size_t)b * NM + pos] = m;
            ctrOf[(size_t)b * NM + pos] = a;
        }
        if (tid == 0) totalPos[b] = NM;
    }
}

// ---------------- stage A: per-8-position segment partial sums --------------
__global__ __launch_bounds__(256) void k_part(
    const float* __restrict__ memF, const float* __restrict__ V, int t,
    const float* __restrict__ cntF,
    const int* __restrict__ lstIdx, const int* __restrict__ ctrOf,
    const int* __restrict__ totalPos,
    float* __restrict__ part, float* __restrict__ partW)
{
    int g = blockIdx.x * 4 + (threadIdx.x >> 6);   // 0..1919
    int l = threadIdx.x & 63;
    int b = g / 480;
    int rem = g - b * 480;
    int seg = rem / 3, c = rem - seg * 3;
    int pos0 = seg * 8;
    if (pos0 >= totalPos[b]) return;
    const int* li = lstIdx + (size_t)b * NM;
    const int* co = ctrOf + (size_t)b * NM;
    int ctr[8]; float wg[8]; float4 xv[8];
#pragma unroll
    for (int i = 0; i < 8; ++i) {
        int p = pos0 + i;
        int cc = co[p];
        int mm = li[p];
        bool pad = cc < 0;
        ctr[i] = pad ? -2 : cc;
        wg[i] = pad ? 0.f : ((mm < NK) ? cntF[b * NK + mm] : 1.0f);
        int mload = pad ? 0 : mm;
        const float4* dr = (mload < NK)
            ? (const float4*)(memF + ((size_t)b * NK + mload) * ND)
            : (const float4*)(V + (((size_t)b * NT + t) * NN + (mload - NK)) * (size_t)ND);
        xv[i] = dr[c * 64 + l];
    }
    float4 acc; float sw; int cur = ctr[0];
    acc.x = wg[0] * xv[0].x; acc.y = wg[0] * xv[0].y;
    acc.z = wg[0] * xv[0].z; acc.w = wg[0] * xv[0].w;
    sw = wg[0];
#pragma unroll
    for (int i = 1; i < 8; ++i) {
        if (ctr[i] != cur) {
            int e = pos0 + i - 1;
            ((float4*)(part + ((size_t)b * NM + e) * ND))[c * 64 + l] = acc;
            if (c == 0 && l == 0) partW[b * NM + e] = sw;
            cur = ctr[i];
            acc.x = wg[i] * xv[i].x; acc.y = wg[i] * xv[i].y;
            acc.z = wg[i] * xv[i].z; acc.w = wg[i] * xv[i].w;
            sw = wg[i];
        } else {
            acc.x += wg[i] * xv[i].x; acc.y += wg[i] * xv[i].y;
            acc.z += wg[i] * xv[i].z; acc.w += wg[i] * xv[i].w;
            sw += wg[i];
        }
    }
    int e = pos0 + 7;
    ((float4*)(part + ((size_t)b * NM + e) * ND))[c * 64 + l] = acc;
    if (c == 0 && l == 0) partW[b * NM + e] = sw;
}

// ---------------- stage B: combine segment partials, write center ----------
// iter1Mode=1: n==0 -> skip entirely (unhit: memH/L + cnP already correct).
// iter1Mode=0: trivial clusters (n==1, pre-self-assigned row) skip entirely;
//              n==0 -> reconstruct center = h+lo from cenHin/cenLin (hit rows only).
__global__ __launch_bounds__(256) void k_upd(
    const f16* __restrict__ cenHin, const f16* __restrict__ cenLin,
    const int2* __restrict__ cb,
    const float* __restrict__ part, const float* __restrict__ partW,
    const unsigned long long* __restrict__ packedIn, int iter1Mode,
    float* __restrict__ Cout, float* __restrict__ cntOut,
    f16* __restrict__ outH, f16* __restrict__ outL,
    float* __restrict__ cnP)
{
    int g = blockIdx.x * 4 + (threadIdx.x >> 6);   // 0..12287
    int lane = threadIdx.x & 63;
    int row = g / 3, c = g - row * 3;              // row = b*NK+k, chunk c
    int b = row >> 10, k = row & 1023;
    int2 cnb = cb[row];
    int n = cnb.x, base = cnb.y;
    if (iter1Mode && n == 0) return;               // unhit: nothing changes
    if (!iter1Mode && n == 1 &&
        (packedIn[(size_t)b * NM + k] >> 32) == 0)
        return;                                    // trivial: nothing changes
    float4 vv;
    float sumw = 0.f;
    if (n == 0) {
        f16x4 hh = ((const f16x4*)(cenHin + (size_t)row * ND))[c * 64 + lane];
        f16x4 ll = ((const f16x4*)(cenLin + (size_t)row * ND))[c * 64 + lane];
        vv.x = (float)hh[0] + (float)ll[0];
        vv.y = (float)hh[1] + (float)ll[1];
        vv.z = (float)hh[2] + (float)ll[2];
        vv.w = (float)hh[3] + (float)ll[3];
        sumw = 0.f;
    } else {
        float4 acc = {0.f, 0.f, 0.f, 0.f};
        int last = base + n - 1;
        int s1 = last >> 3;
        for (int s = base >> 3; s <= s1; ++s) {
            int e = (8 * s + 7 < last) ? (8 * s + 7) : last;
            float4 x = ((const float4*)(part + ((size_t)b * NM + e) * ND))[c * 64 + lane];
            acc.x += x.x; acc.y += x.y; acc.z += x.z; acc.w += x.w;
            sumw += partW[b * NM + e];
        }
        float inv = 1.0f / (sumw + 1e-8f);
        vv.x = acc.x * inv; vv.y = acc.y * inv; vv.z = acc.z * inv; vv.w = acc.w * inv;
    }
    if (!iter1Mode)
        ((float4*)(Cout + (size_t)row * ND))[c * 64 + lane] = vv;
    f16x4 h, lo;
    h[0] = (f16)vv.x; lo[0] = (f16)(vv.x - (float)h[0]);
    h[1] = (f16)vv.y; lo[1] = (f16)(vv.y - (float)h[1]);
    h[2] = (f16)vv.z; lo[2] = (f16)(vv.z - (float)h[2]);
    h[3] = (f16)vv.w; lo[3] = (f16)(vv.w - (float)h[3]);
    ((f16x4*)(outH + (size_t)row * ND))[c * 64 + lane] = h;
    ((f16x4*)(outL + (size_t)row * ND))[c * 64 + lane] = lo;
    float s2 = vv.x * vv.x + vv.y * vv.y + vv.z * vv.z + vv.w * vv.w;
#pragma unroll
    for (int off = 32; off; off >>= 1) s2 += __shfl_xor(s2, off);
    if (lane == 0) cnP[row * 3 + c] = s2;
    if (lane == 0 && c == 0) cntOut[row] = sumw;
}

// ---------------- final: publish memory to d_out ----------------
__global__ __launch_bounds__(256) void k_copy(const float* __restrict__ memF,
                                              float* __restrict__ out) {
    size_t i = (size_t)blockIdx.x * 256 + threadIdx.x;   // 786432 float4
    ((float4*)out)[i] = ((const float4*)memF)[i];
}

// ---------------- host ----------------
extern "C" void kernel_launch(void* const* d_in, const int* in_sizes, int n_in,
                              void* d_out, int out_size, void* d_ws, size_t ws_size,
                              hipStream_t stream) {
    const float* V = (const float*)d_in[0];
    float* out = (float*)d_out;
    char* p = (char*)d_ws;
    auto take = [&](size_t bytes) { char* r = p; p += (bytes + 255) & ~(size_t)255; return r; };

    const size_t fixedBytes = 60ull * 1024 * 1024;
    const size_t fullTokBytes = 2ull * NB * NFRAMES * NN * ND * 2;
    const bool full = ws_size >= fixedBytes + fullTokBytes;
    const size_t tokBS = full ? (size_t)NFRAMES * NN * ND : (size_t)NN * ND;

    float* memF = (float*)take((size_t)NB * NK * ND * 4);
    float* cnt  = (float*)take(NB * NK * 4);
    float* cntS = (float*)take(NB * NK * 4);
    float* cnP  = (float*)take(NB * NK * 3 * 4);
    unsigned long long* packed0 = (unsigned long long*)take(NB * NM * 8);
    unsigned long long* packed1 = (unsigned long long*)take(NB * NM * 8);
    int2* cbBuf  = (int2*)take(NB * NK * 8);
    int*  lstIdx = (int*)take(NB * NM * 4);
    int*  ctrOf  = (int*)take(NB * NM * 4);
    int*  totalPos = (int*)take(NB * 4);
    int*  scoreIdxTok = (int*)take(NB * 512 * 4);
    int*  scoreIdx2   = (int*)take(NB * 512 * 4);
    int*  hitF   = (int*)take(NB * NK * 4);
    float* partW = (float*)take(NB * NM * 4);
    float* partB = (float*)take((size_t)NB * NM * ND * 4);
    f16* memH = (f16*)take((size_t)NB * NK * ND * 2);
    f16* memL = (f16*)take((size_t)NB * NK * ND * 2);
    f16* cenH = (f16*)take((size_t)NB * NK * ND * 2);
    f16* cenL = (f16*)take((size_t)NB * NK * ND * 2);
    f16* tokH = (f16*)take((size_t)NB * tokBS * 2);
    f16* tokL = (f16*)take((size_t)NB * tokBS * 2);

    k_init<<<1024, 256, 0, stream>>>(V, memF, cnt, memH, memL, cnP, packed0, scoreIdxTok);
    if (full)
        k_prep<<<NB * NFRAMES * NN / 4, 256, 0, stream>>>(V, NINIT, NFRAMES, tokH, tokL, tokBS);

    for (int f = 0; f < NFRAMES; ++f) {
        int t = NINIT + f;
        const f16* tH = full ? tokH + (size_t)f * NN * ND : tokH;
        const f16* tL = full ? tokL + (size_t)f * NN * ND : tokL;

        if (!full)
            k_prep<<<NB * NN / 4, 256, 0, stream>>>(V, t, 1, tokH, tokL, tokBS);

        // iter 1: score 256 tokens vs memory centers (M=256, 4 mTiles).
        k_scoreX<<<256, 512, 0, stream>>>(scoreIdxTok, 4, memH, memL, tH, tL, tokBS,
                                          memH, memL, nullptr, cnP, packed0);
        k_lists<<<NB, 1024, 0, stream>>>(packed0, 1, packed1, cbBuf, lstIdx, ctrOf,
                                         totalPos, scoreIdx2, hitF);
        k_part<<<480, 256, 0, stream>>>(memF, V, t, cnt, lstIdx, ctrOf, totalPos, partB, partW);
        k_upd<<<3072, 256, 0, stream>>>(cenH, cenL, cbBuf, partB, partW,
                                        packed1, 1, memF, cntS, cenH, cenL, cnP);

        // iter 2: score tokens + hit rows (M<=512) vs temp centers (hitF-selected);
        // unhit memory rows provably self-assign (pre-written in packed1).
        k_scoreX<<<512, 512, 0, stream>>>(scoreIdx2, 8, memH, memL, tH, tL, tokBS,
                                          cenH, cenL, hitF, cnP, packed1);
        k_lists<<<NB, 1024, 0, stream>>>(packed1, 0, packed0, cbBuf, lstIdx, ctrOf,
                                         totalPos, scoreIdx2, hitF);
        k_part<<<480, 256, 0, stream>>>(memF, V, t, cnt, lstIdx, ctrOf, totalPos, partB, partW);
        k_upd<<<3072, 256, 0, stream>>>(cenH, cenL, cbBuf, partB, partW,
                                        packed1, 0, memF, cnt, memH, memL, cnP);
    }

    k_copy<<<3072, 256, 0, stream>>>(memF, out);
}

// Round 17
// 2306.584 us; speedup vs baseline: 1.3650x; 1.0278x over previous
//
#include <hip/hip_runtime.h>

#define NB 4
#define NT 32
#define ND 768
#define NK 1024
#define NN 256
#define NINIT 4
#define NFRAMES 28
#define NM 1280

typedef _Float16 f16;
typedef f16 f16x8 __attribute__((ext_vector_type(8)));
typedef f16 f16x4 __attribute__((ext_vector_type(4)));
typedef float f32x4 __attribute__((ext_vector_type(4)));

#define GLOAD_LDS(g, s) __builtin_amdgcn_global_load_lds( \
    (const __attribute__((address_space(1))) void*)(g),   \
    (__attribute__((address_space(3))) void*)(s), 16, 0, 0)

// row-dependent XOR swizzle, closed within a 64-byte row (bits 4-5 only).
__device__ __forceinline__ int swz(int r) { return ((r >> 1) & 3) << 4; }

// ---------------- init: mem copy, counts=1, f16 split, cnorm partials, reset --
__global__ __launch_bounds__(256) void k_init(
    const float* __restrict__ V, float* __restrict__ memF, float* __restrict__ cnt,
    f16* __restrict__ mH, f16* __restrict__ mL,
    float* __restrict__ cnP, unsigned long long* __restrict__ packed0,
    int* __restrict__ scoreIdxTok)
{
    int gid = blockIdx.x * 256 + threadIdx.x;
    if (gid < NB * 512) {                      // constant iter1 score index list
        int i = gid & 511;
        scoreIdxTok[gid] = (i < 256) ? NK + i : -1;
    }
    int row = blockIdx.x * 4 + (threadIdx.x >> 6);   // 0..4095
    int lane = threadIdx.x & 63;
    int b = row >> 10, k = row & 1023;
    const float4* src = (const float4*)(V + ((size_t)b * NT * NN + k) * ND);
    float4* mrow = (float4*)(memF + (size_t)row * ND);
    f16x4* hrow = (f16x4*)(mH + (size_t)row * ND);
    f16x4* lrow = (f16x4*)(mL + (size_t)row * ND);
    float s2 = 0.f;
#pragma unroll
    for (int jj = 0; jj < 3; ++jj) {
        float4 x = src[lane + 64 * jj];
        mrow[lane + 64 * jj] = x;
        f16x4 h, lo;
        h[0] = (f16)x.x; lo[0] = (f16)(x.x - (float)h[0]);
        h[1] = (f16)x.y; lo[1] = (f16)(x.y - (float)h[1]);
        h[2] = (f16)x.z; lo[2] = (f16)(x.z - (float)h[2]);
        h[3] = (f16)x.w; lo[3] = (f16)(x.w - (float)h[3]);
        hrow[lane + 64 * jj] = h;
        lrow[lane + 64 * jj] = lo;
        s2 += x.x * x.x + x.y * x.y + x.z * x.z + x.w * x.w;
    }
#pragma unroll
    for (int off = 32; off; off >>= 1) s2 += __shfl_xor(s2, off);
    if (lane == 0) {
        cnP[row * 3] = s2; cnP[row * 3 + 1] = 0.f; cnP[row * 3 + 2] = 0.f;
        cnt[row] = 1.0f; packed0[(size_t)b * NM + k] = ~0ull;
    }
    if (lane == 1 && k < NN) packed0[(size_t)b * NM + NK + k] = ~0ull;
}

// ---------------- token split: frames t0..t0+nF-1 -> slots 0..nF-1 ----------
__global__ __launch_bounds__(256) void k_prep(
    const float* __restrict__ V, int t0, int nF,
    f16* __restrict__ tokH, f16* __restrict__ tokL, size_t tokBS)
{
    int g = blockIdx.x * 4 + (threadIdx.x >> 6);
    int lane = threadIdx.x & 63;
    int perB = nF * NN;
    if (g >= NB * perB) return;
    int b = g / perB;
    int rem = g - b * perB;
    int fi = rem / NN, n = rem - fi * NN;
    const float4* src = (const float4*)(V + (((size_t)b * NT + t0 + fi) * NN + n) * ND);
    f16x4* hrow = (f16x4*)(tokH + (size_t)b * tokBS + (size_t)(fi * NN + n) * ND);
    f16x4* lrow = (f16x4*)(tokL + (size_t)b * tokBS + (size_t)(fi * NN + n) * ND);
#pragma unroll
    for (int jj = 0; jj < 3; ++jj) {
        float4 x = src[lane + 64 * jj];
        f16x4 h, lo;
        h[0] = (f16)x.x; lo[0] = (f16)(x.x - (float)h[0]);
        h[1] = (f16)x.y; lo[1] = (f16)(x.y - (float)h[1]);
        h[2] = (f16)x.z; lo[2] = (f16)(x.z - (float)h[2]);
        h[3] = (f16)x.w; lo[3] = (f16)(x.w - (float)h[3]);
        hrow[lane + 64 * jj] = h;
        lrow[lane + 64 * jj] = lo;
    }
}

// -------- index-gathered MFMA score: MT=64 split-D 8-wave blocks ------------
// Double-buffered LDS + counted vmcnt (R8-validated STAGE pattern).
__global__ __launch_bounds__(512) void k_scoreX(
    const int* __restrict__ sidx, int mTiles,
    const f16* __restrict__ MH, const f16* __restrict__ ML,
    const f16* __restrict__ TH, const f16* __restrict__ TL, size_t tokBS,
    const f16* __restrict__ BH, const f16* __restrict__ BL,
    const int* __restrict__ hitF,
    const float* __restrict__ cnP,
    unsigned long long* __restrict__ packed)
{
    constexpr int MT = 64;
    constexpr int FM = 2;
    constexpr int QROWS = 32;
    constexpr int ASL = 4;
    constexpr int SLOTS = 16;
    constexpr int SPW = 4;
    constexpr int RSZ = SLOTS * 1024;        // 16 KB per D-half region

    __shared__ float4 ldsbuf[2 * SLOTS * 128];   // 64 KB: 2 chunk-buffers x 32 KB
    char* lds = (char*)ldsbuf;

    int bid = blockIdx.x;
    int cpx = (int)gridDim.x >> 3;
    int sz = (bid & 7) * cpx + (bid >> 3);   // XCD-aware (grid % 8 == 0)
    int pb = mTiles * 16;
    int b = sz / pb;
    int rem = sz - b * pb;
    int mt = rem >> 4, kt = rem & 15;
    const int* sb = sidx + b * 512;
    if (sb[mt * MT] < 0) return;             // fully-padded M tile (monotone pad)
    int tid = threadIdx.x;
    int w = tid >> 6, l = tid & 63;
    int h = w >> 2, q = w & 3;
    int wm = q >> 1, wk = q & 1;
    const int REG = h * RSZ;

    const char* sp[SPW];
#pragma unroll
    for (int i = 0; i < SPW; ++i) {
        int slot = q * SPW + i;
        const f16* base; int r;
        if (slot < ASL) {
            r = slot * 16 + (l >> 2);
            int rid = sb[mt * MT + r]; if (rid < 0) rid = 0;
            base = (rid < NK) ? MH + ((size_t)b * NK + rid) * ND
                              : TH + (size_t)b * tokBS + (size_t)(rid - NK) * ND;
        } else if (slot < 2 * ASL) {
            r = (slot - ASL) * 16 + (l >> 2);
            int rid = sb[mt * MT + r]; if (rid < 0) rid = 0;
            base = (rid < NK) ? ML + ((size_t)b * NK + rid) * ND
                              : TL + (size_t)b * tokBS + (size_t)(rid - NK) * ND;
        } else if (slot < 2 * ASL + 4) {
            r = (slot - 2 * ASL) * 16 + (l >> 2);
            int kc = kt * 64 + r;
            const f16* bb = BH;
            if (hitF && !hitF[b * NK + kc]) bb = MH;
            base = bb + ((size_t)b * NK + kc) * ND;
        } else {
            r = (slot - 2 * ASL - 4) * 16 + (l >> 2);
            int kc = kt * 64 + r;
            const f16* bb = BL;
            if (hitF && !hitF[b * NK + kc]) bb = ML;
            base = bb + ((size_t)b * NK + kc) * ND;
        }
        int colB = ((l & 3) * 16) ^ swz(r);
        sp[i] = (const char*)base + h * 768 + colB;
    }

    int aoffH[FM], aoffL[FM], boffH[2], boffL[2];
#pragma unroll
    for (int mi = 0; mi < FM; ++mi) {
        int r = wm * QROWS + mi * 16 + (l & 15);
        int off = r * 64 + (((l >> 4) * 16) ^ swz(r));
        aoffH[mi] = REG + off;
        aoffL[mi] = REG + ASL * 1024 + off;
    }
#pragma unroll
    for (int nj = 0; nj < 2; ++nj) {
        int rB = wk * 32 + nj * 16 + (l & 15);
        int off = rB * 64 + (((l >> 4) * 16) ^ swz(rB));
        boffH[nj] = REG + 2 * ASL * 1024 + off;
        boffL[nj] = REG + 2 * ASL * 1024 + 4096 + off;
    }

    f32x4 acc[FM][2] = {};

#define STAGEX(bufbase)                                                   \
    _Pragma("unroll")                                                     \
    for (int i = 0; i < SPW; ++i) {                                       \
        GLOAD_LDS(sp[i], lds + (bufbase) + REG + (q * SPW + i) * 1024);   \
        sp[i] += 64;                                                      \
    }

    STAGEX(0);                                   // prologue: chunk 0 -> buf0
    for (int c = 0; c < 12; ++c) {
        int cur = (c & 1) << 15;                 // 0 or 32768
        if (c < 11) {
            STAGEX(cur ^ 32768);                 // chunk c+1 -> other buffer
            asm volatile("s_waitcnt vmcnt(4)" ::: "memory");   // chunk c landed
        } else {
            asm volatile("s_waitcnt vmcnt(0)" ::: "memory");
        }
        __builtin_amdgcn_s_barrier();
        __builtin_amdgcn_sched_barrier(0);
        f16x8 ah[FM], al[FM], bh[2], bl[2];
#pragma unroll
        for (int mi = 0; mi < FM; ++mi) {
            ah[mi] = *(const f16x8*)(lds + cur + aoffH[mi]);
            al[mi] = *(const f16x8*)(lds + cur + aoffL[mi]);
        }
#pragma unroll
        for (int nj = 0; nj < 2; ++nj) {
            bh[nj] = *(const f16x8*)(lds + cur + boffH[nj]);
            bl[nj] = *(const f16x8*)(lds + cur + boffL[nj]);
        }
#pragma unroll
        for (int mi = 0; mi < FM; ++mi)
#pragma unroll
            for (int nj = 0; nj < 2; ++nj) {
                acc[mi][nj] = __builtin_amdgcn_mfma_f32_16x16x32_f16(ah[mi], bh[nj], acc[mi][nj], 0, 0, 0);
                acc[mi][nj] = __builtin_amdgcn_mfma_f32_16x16x32_f16(ah[mi], bl[nj], acc[mi][nj], 0, 0, 0);
                acc[mi][nj] = __builtin_amdgcn_mfma_f32_16x16x32_f16(al[mi], bh[nj], acc[mi][nj], 0, 0, 0);
            }
        __builtin_amdgcn_sched_barrier(0);
        __builtin_amdgcn_s_barrier();
    }
    __syncthreads();                             // all reads done; reuse buffer 0

    int coff = q * (QROWS * 128) + l * 16;
    if (h == 1) {
#pragma unroll
        for (int mi = 0; mi < FM; ++mi)
#pragma unroll
            for (int nj = 0; nj < 2; ++nj)
                *(f32x4*)(lds + coff + (mi * 2 + nj) * 1024) = acc[mi][nj];
    }
    __syncthreads();
    if (h != 0) return;
#pragma unroll
    for (int mi = 0; mi < FM; ++mi)
#pragma unroll
        for (int nj = 0; nj < 2; ++nj)
            acc[mi][nj] += *(const f32x4*)(lds + coff + (mi * 2 + nj) * 1024);

    int colb = kt * 64 + wk * 32 + (l & 15);
    float cn[2];
#pragma unroll
    for (int nj = 0; nj < 2; ++nj) {
        int kc = b * NK + colb + nj * 16;
        cn[nj] = cnP[kc * 3] + cnP[kc * 3 + 1] + cnP[kc * 3 + 2];
    }
    size_t pbase = (size_t)b * NM;
#pragma unroll
    for (int mi = 0; mi < FM; ++mi) {
#pragma unroll
        for (int rg = 0; rg < 4; ++rg) {
            float bv = 1e30f; int bi = 0;
#pragma unroll
            for (int nj = 0; nj < 2; ++nj) {
                float s = cn[nj] - 2.0f * acc[mi][nj][rg];
                int ki = colb + nj * 16;
                if (s < bv) { bv = s; bi = ki; }
            }
#pragma unroll
            for (int off = 1; off < 16; off <<= 1) {
                float ov = __shfl_xor(bv, off);
                int   oi = __shfl_xor(bi, off);
                if (ov < bv || (ov == bv && oi < bi)) { bv = ov; bi = oi; }
            }
            if ((l & 15) == 0) {
                int Rt = mt * MT + wm * QROWS + mi * 16 + (l >> 4) * 4 + rg;
                int rid = sb[Rt];
                if (rid >= 0) {
                    unsigned u = __float_as_uint(bv);
                    unsigned key = (u >> 31) ? ~u : (u | 0x80000000u);
                    atomicMin(&packed[pbase + rid],
                              ((unsigned long long)key << 32) | (unsigned)bi);
                }
            }
        }
    }
}

// ---------------- build CSR lists; iter1: +scoreIdx2/hitF; iter2: compacted --
__global__ __launch_bounds__(1024) void k_lists(
    const unsigned long long* __restrict__ packed, int selfSeed,
    unsigned long long* __restrict__ packedOther,
    int2* __restrict__ cb, int* __restrict__ lstIdx, int* __restrict__ ctrOf,
    int* __restrict__ totalPos, int* __restrict__ scoreIdx2,
    int* __restrict__ hitF)
{
    __shared__ int cntL[NK];
    __shared__ int wsum[16];
    __shared__ int hwsum[16];
    __shared__ int cursor[NK];
    __shared__ int aSh[NM];
    __shared__ int unhSh[NK];
    __shared__ int totSh, hitSh;
    int b = blockIdx.x, tid = threadIdx.x;
    cntL[tid] = 0;
    __syncthreads();
    if (selfSeed) {
        if (tid < NN) {
            int a = (int)(unsigned)(packed[(size_t)b * NM + NK + tid] & 0xffffffffull);
            aSh[tid] = a;
            atomicAdd(&cntL[a], 1);
        }
    } else {
        for (int m = tid; m < NM; m += 1024) {
            unsigned long long pk = packed[(size_t)b * NM + m];
            int a = (int)(unsigned)(pk & 0xffffffffull);
            aSh[m] = a;
            atomicAdd(&cntL[a], 1);
            if (m < NK) unhSh[m] = ((pk >> 32) == 0) ? 1 : 0;
        }
    }
    for (int m = tid; m < NM; m += 1024)
        packedOther[(size_t)b * NM + m] = ~0ull;
    __syncthreads();
    int v0 = cntL[tid];
    int triv = (!selfSeed && v0 == 1 && unhSh[tid]) ? 1 : 0;
    int v = selfSeed ? (v0 ? v0 + 1 : 0) : (triv ? 0 : v0);
    int hit = (selfSeed && v0 > 0) ? 1 : 0;
    int lane = tid & 63, wv = tid >> 6;
    int x = v, hx = hit;
#pragma unroll
    for (int off = 1; off < 64; off <<= 1) {
        int y = __shfl_up(x, off);
        int hy = __shfl_up(hx, off);
        if (lane >= off) { x += y; hx += hy; }
    }
    if (lane == 63) { wsum[wv] = x; hwsum[wv] = hx; }
    __syncthreads();
    if (tid < 16) {
        int s = wsum[tid];
        int e = s;
#pragma unroll
        for (int off = 1; off < 16; off <<= 1) {
            int y = __shfl_up(e, off, 16);
            if (tid >= off) e += y;
        }
        wsum[tid] = e - s;
    } else if (tid < 32) {
        int s = hwsum[tid - 16];
        int e = s;
#pragma unroll
        for (int off = 1; off < 16; off <<= 1) {
            int y = __shfl_up(e, off, 16);
            if ((tid - 16) >= off) e += y;
        }
        hwsum[tid - 16] = e - s;
    }
    __syncthreads();
    int base = x + wsum[wv] - v;               // exclusive prefix of v (compacted)
    int hb = hx + hwsum[wv] - hit;             // exclusive prefix of hits
    cursor[tid] = base + ((selfSeed && v0) ? 1 : 0);
    // cb.x = real member count (iter2 trivial check needs v0); base = compacted.
    cb[b * NK + tid] = make_int2(selfSeed ? v : v0, base);
    if (selfSeed && v0) {                      // self entry first (row = tid)
        lstIdx[(size_t)b * NM + base] = tid;
        ctrOf[(size_t)b * NM + base] = tid;
    }
    if (selfSeed) {
        hitF[b * NK + tid] = hit;
        packedOther[(size_t)b * NM + tid] = hit ? ~0ull : (unsigned long long)(unsigned)tid;
        if (tid < NN) packedOther[(size_t)b * NM + NK + tid] = ~0ull;
        if (hit) scoreIdx2[b * 512 + 256 + hb] = tid;
        if (tid < 256) scoreIdx2[b * 512 + tid] = NK + tid;
        if (tid == 1023) hitSh = hb + hit;
    }
    if (tid == 1023) totSh = base + v;
    __syncthreads();
    if (selfSeed) {
        if (tid < NN) {
            int a = aSh[tid];
            int pos = atomicAdd(&cursor[a], 1);
            lstIdx[(size_t)b * NM + pos] = NK + tid;
            ctrOf[(size_t)b * NM + pos] = a;
        }
        int H = hitSh;
        if (tid >= H && tid < 256) scoreIdx2[b * 512 + 256 + tid] = -1;
    } else {
        for (int m = tid; m < NM; m += 1024) {
            int a = aSh[m];
            if (cntL[a] == 1 && unhSh[a]) continue;      // trivial cluster member
            int pos = atomicAdd(&cursor[a], 1);
            lstIdx[(size_t)b * NM + pos] = m;
            ctrOf[(size_t)b * NM + pos] = a;
        }
    }
    if (tid == 0) {
        int total = totSh;
        int padEnd = (total + 7) & ~7;
        for (int p2 = total; p2 < padEnd; ++p2) {
            lstIdx[(size_t)b * NM + p2] = 0;
            ctrOf[(size_t)b * NM + p2] = -1;
        }
        totalPos[b] = total;
    }
}

// ---------------- stage A: per-8-position segment partial sums --------------
__global__ __launch_bounds__(256) void k_part(
    const float* __restrict__ memF, const float* __restrict__ V, int t,
    const float* __restrict__ cntF,
    const int* __restrict__ lstIdx, const int* __restrict__ ctrOf,
    const int* __restrict__ totalPos,
    float* __restrict__ part, float* __restrict__ partW)
{
    int g = blockIdx.x * 4 + (threadIdx.x >> 6);   // 0..1919
    int l = threadIdx.x & 63;
    int b = g / 480;
    int rem = g - b * 480;
    int seg = rem / 3, c = rem - seg * 3;
    int pos0 = seg * 8;
    if (pos0 >= totalPos[b]) return;
    const int* li = lstIdx + (size_t)b * NM;
    const int* co = ctrOf + (size_t)b * NM;
    int ctr[8]; float wg[8]; float4 xv[8];
#pragma unroll
    for (int i = 0; i < 8; ++i) {
        int p = pos0 + i;
        int cc = co[p];
        int mm = li[p];
        bool pad = cc < 0;
        ctr[i] = pad ? -2 : cc;
        wg[i] = pad ? 0.f : ((mm < NK) ? cntF[b * NK + mm] : 1.0f);
        int mload = pad ? 0 : mm;
        const float4* dr = (mload < NK)
            ? (const float4*)(memF + ((size_t)b * NK + mload) * ND)
            : (const float4*)(V + (((size_t)b * NT + t) * NN + (mload - NK)) * (size_t)ND);
        xv[i] = dr[c * 64 + l];
    }
    float4 acc; float sw; int cur = ctr[0];
    acc.x = wg[0] * xv[0].x; acc.y = wg[0] * xv[0].y;
    acc.z = wg[0] * xv[0].z; acc.w = wg[0] * xv[0].w;
    sw = wg[0];
#pragma unroll
    for (int i = 1; i < 8; ++i) {
        if (ctr[i] != cur) {
            int e = pos0 + i - 1;
            ((float4*)(part + ((size_t)b * NM + e) * ND))[c * 64 + l] = acc;
            if (c == 0 && l == 0) partW[b * NM + e] = sw;
            cur = ctr[i];
            acc.x = wg[i] * xv[i].x; acc.y = wg[i] * xv[i].y;
            acc.z = wg[i] * xv[i].z; acc.w = wg[i] * xv[i].w;
            sw = wg[i];
        } else {
            acc.x += wg[i] * xv[i].x; acc.y += wg[i] * xv[i].y;
            acc.z += wg[i] * xv[i].z; acc.w += wg[i] * xv[i].w;
            sw += wg[i];
        }
    }
    int e = pos0 + 7;
    ((float4*)(part + ((size_t)b * NM + e) * ND))[c * 64 + l] = acc;
    if (c == 0 && l == 0) partW[b * NM + e] = sw;
}

// ---------------- stage B: combine segment partials, write center ----------
// iter1Mode=1: n==0 -> skip entirely (unhit: memH/L + cnP already correct).
// iter1Mode=0: trivial clusters (n==1, pre-self-assigned row) skip entirely;
//              n==0 -> reconstruct center = h+lo from cenHin/cenLin (hit rows only).
__global__ __launch_bounds__(256) void k_upd(
    const f16* __restrict__ cenHin, const f16* __restrict__ cenLin,
    const int2* __restrict__ cb,
    const float* __restrict__ part, const float* __restrict__ partW,
    const unsigned long long* __restrict__ packedIn, int iter1Mode,
    float* __restrict__ Cout, float* __restrict__ cntOut,
    f16* __restrict__ outH, f16* __restrict__ outL,
    float* __restrict__ cnP)
{
    int g = blockIdx.x * 4 + (threadIdx.x >> 6);   // 0..12287
    int lane = threadIdx.x & 63;
    int row = g / 3, c = g - row * 3;              // row = b*NK+k, chunk c
    int b = row >> 10, k = row & 1023;
    int2 cnb = cb[row];
    int n = cnb.x, base = cnb.y;
    if (iter1Mode && n == 0) return;               // unhit: nothing changes
    if (!iter1Mode && n == 1 &&
        (packedIn[(size_t)b * NM + k] >> 32) == 0)
        return;                                    // trivial: nothing changes
    float4 vv;
    float sumw = 0.f;
    if (n == 0) {
        f16x4 hh = ((const f16x4*)(cenHin + (size_t)row * ND))[c * 64 + lane];
        f16x4 ll = ((const f16x4*)(cenLin + (size_t)row * ND))[c * 64 + lane];
        vv.x = (float)hh[0] + (float)ll[0];
        vv.y = (float)hh[1] + (float)ll[1];
        vv.z = (float)hh[2] + (float)ll[2];
        vv.w = (float)hh[3] + (float)ll[3];
        sumw = 0.f;
    } else {
        float4 acc = {0.f, 0.f, 0.f, 0.f};
        int last = base + n - 1;
        int s1 = last >> 3;
        for (int s = base >> 3; s <= s1; ++s) {
            int e = (8 * s + 7 < last) ? (8 * s + 7) : last;
            float4 x = ((const float4*)(part + ((size_t)b * NM + e) * ND))[c * 64 + lane];
            acc.x += x.x; acc.y += x.y; acc.z += x.z; acc.w += x.w;
            sumw += partW[b * NM + e];
        }
        float inv = 1.0f / (sumw + 1e-8f);
        vv.x = acc.x * inv; vv.y = acc.y * inv; vv.z = acc.z * inv; vv.w = acc.w * inv;
    }
    if (!iter1Mode)
        ((float4*)(Cout + (size_t)row * ND))[c * 64 + lane] = vv;
    f16x4 h, lo;
    h[0] = (f16)vv.x; lo[0] = (f16)(vv.x - (float)h[0]);
    h[1] = (f16)vv.y; lo[1] = (f16)(vv.y - (float)h[1]);
    h[2] = (f16)vv.z; lo[2] = (f16)(vv.z - (float)h[2]);
    h[3] = (f16)vv.w; lo[3] = (f16)(vv.w - (float)h[3]);
    ((f16x4*)(outH + (size_t)row * ND))[c * 64 + lane] = h;
    ((f16x4*)(outL + (size_t)row * ND))[c * 64 + lane] = lo;
    float s2 = vv.x * vv.x + vv.y * vv.y + vv.z * vv.z + vv.w * vv.w;
#pragma unroll
    for (int off = 32; off; off >>= 1) s2 += __shfl_xor(s2, off);
    if (lane == 0) cnP[row * 3 + c] = s2;
    if (lane == 0 && c == 0) cntOut[row] = sumw;
}

// ---------------- final: publish memory to d_out ----------------
__global__ __launch_bounds__(256) void k_copy(const float* __restrict__ memF,
                                              float* __restrict__ out) {
    size_t i = (size_t)blockIdx.x * 256 + threadIdx.x;   // 786432 float4
    ((float4*)out)[i] = ((const float4*)memF)[i];
}

// ---------------- host ----------------
extern "C" void kernel_launch(void* const* d_in, const int* in_sizes, int n_in,
                              void* d_out, int out_size, void* d_ws, size_t ws_size,
                              hipStream_t stream) {
    const float* V = (const float*)d_in[0];
    float* out = (float*)d_out;
    char* p = (char*)d_ws;
    auto take = [&](size_t bytes) { char* r = p; p += (bytes + 255) & ~(size_t)255; return r; };

    const size_t fixedBytes = 60ull * 1024 * 1024;
    const size_t fullTokBytes = 2ull * NB * NFRAMES * NN * ND * 2;
    const bool full = ws_size >= fixedBytes + fullTokBytes;
    const size_t tokBS = full ? (size_t)NFRAMES * NN * ND : (size_t)NN * ND;

    float* memF = (float*)take((size_t)NB * NK * ND * 4);
    float* cnt  = (float*)take(NB * NK * 4);
    float* cntS = (float*)take(NB * NK * 4);
    float* cnP  = (float*)take(NB * NK * 3 * 4);
    unsigned long long* packed0 = (unsigned long long*)take(NB * NM * 8);
    unsigned long long* packed1 = (unsigned long long*)take(NB * NM * 8);
    int2* cbBuf  = (int2*)take(NB * NK * 8);
    int*  lstIdx = (int*)take(NB * NM * 4);
    int*  ctrOf  = (int*)take(NB * NM * 4);
    int*  totalPos = (int*)take(NB * 4);
    int*  scoreIdxTok = (int*)take(NB * 512 * 4);
    int*  scoreIdx2   = (int*)take(NB * 512 * 4);
    int*  hitF   = (int*)take(NB * NK * 4);
    float* partW = (float*)take(NB * NM * 4);
    float* partB = (float*)take((size_t)NB * NM * ND * 4);
    f16* memH = (f16*)take((size_t)NB * NK * ND * 2);
    f16* memL = (f16*)take((size_t)NB * NK * ND * 2);
    f16* cenH = (f16*)take((size_t)NB * NK * ND * 2);
    f16* cenL = (f16*)take((size_t)NB * NK * ND * 2);
    f16* tokH = (f16*)take((size_t)NB * tokBS * 2);
    f16* tokL = (f16*)take((size_t)NB * tokBS * 2);

    k_init<<<1024, 256, 0, stream>>>(V, memF, cnt, memH, memL, cnP, packed0, scoreIdxTok);
    if (full)
        k_prep<<<NB * NFRAMES * NN / 4, 256, 0, stream>>>(V, NINIT, NFRAMES, tokH, tokL, tokBS);

    for (int f = 0; f < NFRAMES; ++f) {
        int t = NINIT + f;
        const f16* tH = full ? tokH + (size_t)f * NN * ND : tokH;
        const f16* tL = full ? tokL + (size_t)f * NN * ND : tokL;

        if (!full)
            k_prep<<<NB * NN / 4, 256, 0, stream>>>(V, t, 1, tokH, tokL, tokBS);

        // iter 1: score 256 tokens vs memory centers (M=256, 4 mTiles).
        k_scoreX<<<256, 512, 0, stream>>>(scoreIdxTok, 4, memH, memL, tH, tL, tokBS,
                                          memH, memL, nullptr, cnP, packed0);
        k_lists<<<NB, 1024, 0, stream>>>(packed0, 1, packed1, cbBuf, lstIdx, ctrOf,
                                         totalPos, scoreIdx2, hitF);
        k_part<<<480, 256, 0, stream>>>(memF, V, t, cnt, lstIdx, ctrOf, totalPos, partB, partW);
        k_upd<<<3072, 256, 0, stream>>>(cenH, cenL, cbBuf, partB, partW,
                                        packed1, 1, memF, cntS, cenH, cenL, cnP);

        // iter 2: score tokens + hit rows (M<=512) vs temp centers (hitF-selected);
        // unhit memory rows provably self-assign (pre-written in packed1).
        k_scoreX<<<512, 512, 0, stream>>>(scoreIdx2, 8, memH, memL, tH, tL, tokBS,
                                          cenH, cenL, hitF, cnP, packed1);
        k_lists<<<NB, 1024, 0, stream>>>(packed1, 0, packed0, cbBuf, lstIdx, ctrOf,
                                         totalPos, scoreIdx2, hitF);
        k_part<<<480, 256, 0, stream>>>(memF, V, t, cnt, lstIdx, ctrOf, totalPos, partB, partW);
        k_upd<<<3072, 256, 0, stream>>>(cenH, cenL, cbBuf, partB, partW,
                                        packed1, 0, memF, cnt, memH, memL, cnP);
    }

    k_copy<<<3072, 256, 0, stream>>>(memF, out);
}